// Round 1
// baseline (1162.476 us; speedup 1.0000x reference)
//
#include <hip/hip_runtime.h>
#include <hip/hip_bf16.h>

#define NN   100000
#define NE   1600000
#define FHID 128
#define FO3  40
constexpr float EPSV = 1e-5f;

// ---------------- graph prep ----------------

__global__ void count_kernel(const int* __restrict__ dst, int* __restrict__ cnt) {
    int e = blockIdx.x * 256 + threadIdx.x;
    if (e < NE) atomicAdd(&cnt[dst[e]], 1);
}

__global__ void dinv_kernel(const int* __restrict__ cnt, float* __restrict__ dinv) {
    int i = blockIdx.x * 256 + threadIdx.x;
    if (i < NN) dinv[i] = rsqrtf((float)cnt[i] + 1.0f);   // +1 = self loop
}

__global__ __launch_bounds__(1024) void scan_kernel(const int* __restrict__ cnt,
                                                    int* __restrict__ rowptr,
                                                    int* __restrict__ cursor) {
    __shared__ int sums[1024];
    int t = threadIdx.x;
    const int chunk = (NN + 1023) / 1024;   // 98
    int base = t * chunk;
    int lim = base + chunk; if (lim > NN) lim = NN;
    int local = 0;
    for (int i = base; i < lim; ++i) local += cnt[i];
    sums[t] = local;
    __syncthreads();
    for (int off = 1; off < 1024; off <<= 1) {
        int v = (t >= off) ? sums[t - off] : 0;
        __syncthreads();
        sums[t] += v;
        __syncthreads();
    }
    int run = (t == 0) ? 0 : sums[t - 1];
    for (int i = base; i < lim; ++i) {
        rowptr[i] = run; cursor[i] = run; run += cnt[i];
    }
    if (t == 1023) rowptr[NN] = sums[1023];
}

__global__ void fill_kernel(const int* __restrict__ src, const int* __restrict__ dst,
                            int* __restrict__ cursor, int* __restrict__ srcsorted) {
    int e = blockIdx.x * 256 + threadIdx.x;
    if (e < NE) {
        int d = dst[e];
        int pos = atomicAdd(&cursor[d], 1);
        srcsorted[pos] = src[e];
    }
}

// ---------------- batchnorm stats ----------------

__global__ void bnstats_kernel(const float* __restrict__ X, float* __restrict__ stats) {
    int f = threadIdx.x & 127;
    int rg = threadIdx.x >> 7;               // 0..1
    float s = 0.f, s2 = 0.f;
    for (int r = blockIdx.x * 2 + rg; r < NN; r += gridDim.x * 2) {
        float v = X[(size_t)r * 128 + f];
        s += v; s2 += v * v;
    }
    atomicAdd(&stats[f], s);
    atomicAdd(&stats[128 + f], s2);
}

__global__ void bnfinal_kernel(const float* __restrict__ stats, const float* __restrict__ g,
                               const float* __restrict__ be, float* __restrict__ sc) {
    int f = threadIdx.x;                     // 128 threads
    float mu  = stats[f] * (1.0f / NN);
    float var = stats[128 + f] * (1.0f / NN) - mu * mu;
    float rstd = rsqrtf(var + EPSV);
    float scale = g[f] * rstd;
    sc[f]       = scale;
    sc[128 + f] = be[f] - mu * scale;
}

// ---------------- dense GEMMs ----------------
// block (16,16); grid (NN/32, 2). Each thread: nodes {ty, ty+16}, feats [4*tx,4*tx+4) of a 64-col tile.
template<bool BN>
__global__ __launch_bounds__(256) void gemm128_kernel(const float* __restrict__ X,
        const float* __restrict__ W, const float* __restrict__ sc,
        float* __restrict__ Y) {
    __shared__ float Ws[128][64];
    __shared__ float Xs[32][132];
    int tx = threadIdx.x, ty = threadIdx.y;
    int tid = ty * 16 + tx;
    int ftile = blockIdx.y * 64;
    int node0 = blockIdx.x * 32;

    for (int idx = tid * 4; idx < 128 * 64; idx += 256 * 4) {
        int k = idx >> 6, c = idx & 63;
        float4 w4 = *(const float4*)(W + (size_t)k * 128 + ftile + c);
        *(float4*)&Ws[k][c] = w4;
    }
    for (int idx = tid * 4; idx < 32 * 128; idx += 256 * 4) {
        int n = idx >> 7, f = idx & 127;
        float4 v = *(const float4*)(X + (size_t)(node0 + n) * 128 + f);
        if constexpr (BN) {
            v.x = fmaxf(fmaf(v.x, sc[f],     sc[128 + f]),     0.f);
            v.y = fmaxf(fmaf(v.y, sc[f + 1], sc[128 + f + 1]), 0.f);
            v.z = fmaxf(fmaf(v.z, sc[f + 2], sc[128 + f + 2]), 0.f);
            v.w = fmaxf(fmaf(v.w, sc[f + 3], sc[128 + f + 3]), 0.f);
        }
        *(float4*)&Xs[n][f] = v;
    }
    __syncthreads();

    float4 a0 = {0,0,0,0}, a1 = {0,0,0,0};
    int n0 = ty, n1 = ty + 16;
    #pragma unroll 4
    for (int k = 0; k < 128; ++k) {
        float4 w = *(float4*)&Ws[k][tx * 4];
        float x0 = Xs[n0][k];
        float x1 = Xs[n1][k];
        a0.x = fmaf(x0, w.x, a0.x); a0.y = fmaf(x0, w.y, a0.y);
        a0.z = fmaf(x0, w.z, a0.z); a0.w = fmaf(x0, w.w, a0.w);
        a1.x = fmaf(x1, w.x, a1.x); a1.y = fmaf(x1, w.y, a1.y);
        a1.z = fmaf(x1, w.z, a1.z); a1.w = fmaf(x1, w.w, a1.w);
    }
    *(float4*)(Y + (size_t)(node0 + n0) * 128 + ftile + tx * 4) = a0;
    *(float4*)(Y + (size_t)(node0 + n1) * 128 + ftile + tx * 4) = a1;
}

// block (8,32): tx -> 5 feats, ty -> 1 node. BN always on here.
__global__ __launch_bounds__(256) void gemm40_kernel(const float* __restrict__ X,
        const float* __restrict__ W, const float* __restrict__ sc,
        float* __restrict__ Y) {
    __shared__ float Ws[128][40];
    __shared__ float Xs[32][132];
    int tx = threadIdx.x, ty = threadIdx.y;
    int tid = ty * 8 + tx;
    int node0 = blockIdx.x * 32;

    float* wf = &Ws[0][0];
    for (int idx = tid; idx < 128 * 40; idx += 256) wf[idx] = W[idx];
    for (int idx = tid * 4; idx < 32 * 128; idx += 256 * 4) {
        int n = idx >> 7, f = idx & 127;
        float4 v = *(const float4*)(X + (size_t)(node0 + n) * 128 + f);
        v.x = fmaxf(fmaf(v.x, sc[f],     sc[128 + f]),     0.f);
        v.y = fmaxf(fmaf(v.y, sc[f + 1], sc[128 + f + 1]), 0.f);
        v.z = fmaxf(fmaf(v.z, sc[f + 2], sc[128 + f + 2]), 0.f);
        v.w = fmaxf(fmaf(v.w, sc[f + 3], sc[128 + f + 3]), 0.f);
        *(float4*)&Xs[n][f] = v;
    }
    __syncthreads();

    float acc[5] = {0,0,0,0,0};
    int f0 = tx * 5;
    #pragma unroll 4
    for (int k = 0; k < 128; ++k) {
        float xv = Xs[ty][k];
        #pragma unroll
        for (int j = 0; j < 5; ++j) acc[j] = fmaf(xv, Ws[k][f0 + j], acc[j]);
    }
    float* yp = Y + (size_t)(node0 + ty) * 40 + f0;
    #pragma unroll
    for (int j = 0; j < 5; ++j) yp[j] = acc[j];
}

// ---------------- aggregation ----------------
// one wave (64 lanes) per node, 2 feats per lane
__global__ __launch_bounds__(256) void agg128_kernel(const float* __restrict__ H,
        const int* __restrict__ rowptr, const int* __restrict__ srcs,
        const float* __restrict__ dinv, const float* __restrict__ bias,
        float* __restrict__ out) {
    int wave = threadIdx.x >> 6;
    int lane = threadIdx.x & 63;
    int node = blockIdx.x * 4 + wave;
    int beg = rowptr[node], end = rowptr[node + 1];
    int c = lane * 2;
    float a0 = 0.f, a1 = 0.f;
    int e = beg;
    for (; e + 1 < end; e += 2) {
        int s0 = srcs[e], s1 = srcs[e + 1];
        float w0 = dinv[s0], w1 = dinv[s1];
        float2 h0 = *(const float2*)(H + (size_t)s0 * 128 + c);
        float2 h1 = *(const float2*)(H + (size_t)s1 * 128 + c);
        a0 = fmaf(w0, h0.x, a0); a1 = fmaf(w0, h0.y, a1);
        a0 = fmaf(w1, h1.x, a0); a1 = fmaf(w1, h1.y, a1);
    }
    if (e < end) {
        int s = srcs[e];
        float w = dinv[s];
        float2 h = *(const float2*)(H + (size_t)s * 128 + c);
        a0 = fmaf(w, h.x, a0); a1 = fmaf(w, h.y, a1);
    }
    float di = dinv[node];
    float2 hs = *(const float2*)(H + (size_t)node * 128 + c);
    a0 = di * (a0 + di * hs.x) + bias[c];
    a1 = di * (a1 + di * hs.y) + bias[c + 1];
    *(float2*)(out + (size_t)node * 128 + c) = make_float2(a0, a1);
}

// final layer: aggregate 40 feats + bias + row softmax, fused, writes d_out
__global__ __launch_bounds__(256) void agg40_softmax_kernel(const float* __restrict__ H,
        const int* __restrict__ rowptr, const int* __restrict__ srcs,
        const float* __restrict__ dinv, const float* __restrict__ bias,
        float* __restrict__ out) {
    int wave = threadIdx.x >> 6;
    int lane = threadIdx.x & 63;
    int node = blockIdx.x * 4 + wave;
    int beg = rowptr[node], end = rowptr[node + 1];
    bool act = lane < 40;
    float a = 0.f;
    for (int e = beg; e < end; ++e) {
        int s = srcs[e];
        float w = dinv[s];
        float h = act ? H[(size_t)s * 40 + lane] : 0.f;
        a = fmaf(w, h, a);
    }
    float di = dinv[node];
    float v = -3.0e38f;
    if (act) {
        float hs = H[(size_t)node * 40 + lane];
        v = di * (a + di * hs) + bias[lane];
    }
    float m = v;
    #pragma unroll
    for (int off = 32; off > 0; off >>= 1) m = fmaxf(m, __shfl_xor(m, off));
    float ev = act ? expf(v - m) : 0.f;
    float ssum = ev;
    #pragma unroll
    for (int off = 32; off > 0; off >>= 1) ssum += __shfl_xor(ssum, off);
    if (act) out[(size_t)node * 40 + lane] = ev / ssum;
}

// ---------------- launch ----------------

extern "C" void kernel_launch(void* const* d_in, const int* in_sizes, int n_in,
                              void* d_out, int out_size, void* d_ws, size_t ws_size,
                              hipStream_t stream) {
    const float* x   = (const float*)d_in[0];
    const int*   ei  = (const int*)d_in[1];
    const float* W1  = (const float*)d_in[2];
    const float* b1  = (const float*)d_in[3];
    const float* g1  = (const float*)d_in[4];
    const float* be1 = (const float*)d_in[5];
    const float* W2  = (const float*)d_in[6];
    const float* b2  = (const float*)d_in[7];
    const float* g2  = (const float*)d_in[8];
    const float* be2 = (const float*)d_in[9];
    const float* W3  = (const float*)d_in[10];
    const float* b3  = (const float*)d_in[11];
    float* out = (float*)d_out;
    const int* src = ei;
    const int* dst = ei + NE;

    char* p = (char*)d_ws;
    auto alloc = [&](size_t bytes) { char* r = p; p += (bytes + 255) & ~255ull; return r; };
    int*   cnt       = (int*)  alloc((size_t)NN * 4);
    int*   rowptr    = (int*)  alloc((size_t)(NN + 1) * 4);
    int*   cursor    = (int*)  alloc((size_t)NN * 4);
    int*   srcsorted = (int*)  alloc((size_t)NE * 4);
    float* dinv      = (float*)alloc((size_t)NN * 4);
    float* stats     = (float*)alloc(256 * 4);
    float* sc        = (float*)alloc(256 * 4);
    float* A         = (float*)alloc((size_t)NN * 128 * 4);
    float* B         = (float*)alloc((size_t)NN * 128 * 4);

    hipMemsetAsync(cnt, 0, (size_t)NN * 4, stream);
    count_kernel<<<NE / 256, 256, 0, stream>>>(dst, cnt);
    dinv_kernel<<<(NN + 255) / 256, 256, 0, stream>>>(cnt, dinv);
    scan_kernel<<<1, 1024, 0, stream>>>(cnt, rowptr, cursor);
    fill_kernel<<<NE / 256, 256, 0, stream>>>(src, dst, cursor, srcsorted);

    dim3 gb(16, 16);
    // layer 1
    gemm128_kernel<false><<<dim3(NN / 32, 2), gb, 0, stream>>>(x, W1, nullptr, A);
    agg128_kernel<<<NN / 4, 256, 0, stream>>>(A, rowptr, srcsorted, dinv, b1, B);
    hipMemsetAsync(stats, 0, 256 * 4, stream);
    bnstats_kernel<<<1024, 256, 0, stream>>>(B, stats);
    bnfinal_kernel<<<1, 128, 0, stream>>>(stats, g1, be1, sc);
    // layer 2 (BN+ReLU fused into GEMM X-load)
    gemm128_kernel<true><<<dim3(NN / 32, 2), gb, 0, stream>>>(B, W2, sc, A);
    agg128_kernel<<<NN / 4, 256, 0, stream>>>(A, rowptr, srcsorted, dinv, b2, B);
    hipMemsetAsync(stats, 0, 256 * 4, stream);
    bnstats_kernel<<<1024, 256, 0, stream>>>(B, stats);
    bnfinal_kernel<<<1, 128, 0, stream>>>(stats, g2, be2, sc);
    // layer 3 (BN+ReLU fused) + aggregation + softmax fused
    gemm40_kernel<<<dim3(NN / 32), dim3(8, 32), 0, stream>>>(B, W3, sc, A);
    agg40_softmax_kernel<<<NN / 4, 256, 0, stream>>>(A, rowptr, srcsorted, dinv, b3, out);
}

// Round 2
// 959.760 us; speedup vs baseline: 1.2112x; 1.2112x over previous
//
#include <hip/hip_runtime.h>
#include <hip/hip_bf16.h>

#define NN   100000
#define NE   1600000
#define FHID 128
#define FO3  40
#define SCAN_CHUNK 512
#define NBLK ((NN + SCAN_CHUNK - 1) / SCAN_CHUNK)   // 196
constexpr float EPSV = 1e-5f;

// ---------------- graph prep ----------------

__global__ void count_kernel(const int* __restrict__ dst, int* __restrict__ cnt) {
    int e = blockIdx.x * 256 + threadIdx.x;
    if (e < NE) atomicAdd(&cnt[dst[e]], 1);
}

__global__ void dinv_kernel(const int* __restrict__ cnt, float* __restrict__ dinv) {
    int i = blockIdx.x * 256 + threadIdx.x;
    if (i < NN) dinv[i] = rsqrtf((float)cnt[i] + 1.0f);   // +1 = self loop
}

// ---- 3-phase hierarchical scan (replaces 228us single-block scan) ----

__global__ __launch_bounds__(256) void scan1_kernel(const int* __restrict__ cnt,
                                                    int* __restrict__ blocksum) {
    __shared__ int red[256];
    int t = threadIdx.x;
    int base = blockIdx.x * SCAN_CHUNK + t * 2;
    int v = 0;
    if (base < NN)     v += cnt[base];
    if (base + 1 < NN) v += cnt[base + 1];
    red[t] = v;
    __syncthreads();
    #pragma unroll
    for (int off = 128; off > 0; off >>= 1) {
        if (t < off) red[t] += red[t + off];
        __syncthreads();
    }
    if (t == 0) blocksum[blockIdx.x] = red[0];
}

__global__ __launch_bounds__(256) void scan2_kernel(const int* __restrict__ blocksum,
                                                    int* __restrict__ blockoff,
                                                    int* __restrict__ rowptr_end) {
    __shared__ int s[256];
    int t = threadIdx.x;
    int v = (t < NBLK) ? blocksum[t] : 0;
    s[t] = v;
    __syncthreads();
    #pragma unroll
    for (int off = 1; off < 256; off <<= 1) {
        int u = (t >= off) ? s[t - off] : 0;
        __syncthreads();
        s[t] += u;
        __syncthreads();
    }
    if (t < NBLK) blockoff[t] = s[t] - v;   // exclusive
    if (t == 255) rowptr_end[0] = s[255];   // total = rowptr[NN]
}

__global__ __launch_bounds__(256) void scan3_kernel(const int* __restrict__ cnt,
                                                    const int* __restrict__ blockoff,
                                                    int* __restrict__ rowptr,
                                                    int* __restrict__ cursor) {
    __shared__ int s[256];
    int t = threadIdx.x;
    int base = blockIdx.x * SCAN_CHUNK + t * 2;
    int c0 = (base < NN) ? cnt[base] : 0;
    int c1 = (base + 1 < NN) ? cnt[base + 1] : 0;
    int pair = c0 + c1;
    s[t] = pair;
    __syncthreads();
    #pragma unroll
    for (int off = 1; off < 256; off <<= 1) {
        int u = (t >= off) ? s[t - off] : 0;
        __syncthreads();
        s[t] += u;
        __syncthreads();
    }
    int excl = blockoff[blockIdx.x] + s[t] - pair;
    if (base < NN)     { rowptr[base] = excl;      cursor[base] = excl; }
    if (base + 1 < NN) { rowptr[base + 1] = excl + c0; cursor[base + 1] = excl + c0; }
}

__global__ void fill_kernel(const int* __restrict__ src, const int* __restrict__ dst,
                            int* __restrict__ cursor, int* __restrict__ srcsorted) {
    int e = blockIdx.x * 256 + threadIdx.x;
    if (e < NE) {
        int d = dst[e];
        int pos = atomicAdd(&cursor[d], 1);
        srcsorted[pos] = src[e];
    }
}

// ---------------- batchnorm stats ----------------

__global__ void bnstats_kernel(const float* __restrict__ X, float* __restrict__ stats) {
    int f = threadIdx.x & 127;
    int rg = threadIdx.x >> 7;               // 0..1
    float s = 0.f, s2 = 0.f;
    for (int r = blockIdx.x * 2 + rg; r < NN; r += gridDim.x * 2) {
        float v = X[(size_t)r * 128 + f];
        s += v; s2 += v * v;
    }
    atomicAdd(&stats[f], s);
    atomicAdd(&stats[128 + f], s2);
}

__global__ void bnfinal_kernel(const float* __restrict__ stats, const float* __restrict__ g,
                               const float* __restrict__ be, float* __restrict__ sc) {
    int f = threadIdx.x;                     // 128 threads
    float mu  = stats[f] * (1.0f / NN);
    float var = stats[128 + f] * (1.0f / NN) - mu * mu;
    float rstd = rsqrtf(var + EPSV);
    float scale = g[f] * rstd;
    sc[f]       = scale;
    sc[128 + f] = be[f] - mu * scale;
}

// ---------------- dense GEMMs ----------------
template<bool BN>
__global__ __launch_bounds__(256) void gemm128_kernel(const float* __restrict__ X,
        const float* __restrict__ W, const float* __restrict__ sc,
        float* __restrict__ Y) {
    __shared__ float Ws[128][64];
    __shared__ float Xs[32][132];
    int tx = threadIdx.x, ty = threadIdx.y;
    int tid = ty * 16 + tx;
    int ftile = blockIdx.y * 64;
    int node0 = blockIdx.x * 32;

    for (int idx = tid * 4; idx < 128 * 64; idx += 256 * 4) {
        int k = idx >> 6, c = idx & 63;
        float4 w4 = *(const float4*)(W + (size_t)k * 128 + ftile + c);
        *(float4*)&Ws[k][c] = w4;
    }
    for (int idx = tid * 4; idx < 32 * 128; idx += 256 * 4) {
        int n = idx >> 7, f = idx & 127;
        float4 v = *(const float4*)(X + (size_t)(node0 + n) * 128 + f);
        if constexpr (BN) {
            v.x = fmaxf(fmaf(v.x, sc[f],     sc[128 + f]),     0.f);
            v.y = fmaxf(fmaf(v.y, sc[f + 1], sc[128 + f + 1]), 0.f);
            v.z = fmaxf(fmaf(v.z, sc[f + 2], sc[128 + f + 2]), 0.f);
            v.w = fmaxf(fmaf(v.w, sc[f + 3], sc[128 + f + 3]), 0.f);
        }
        *(float4*)&Xs[n][f] = v;
    }
    __syncthreads();

    float4 a0 = {0,0,0,0}, a1 = {0,0,0,0};
    int n0 = ty, n1 = ty + 16;
    #pragma unroll 4
    for (int k = 0; k < 128; ++k) {
        float4 w = *(float4*)&Ws[k][tx * 4];
        float x0 = Xs[n0][k];
        float x1 = Xs[n1][k];
        a0.x = fmaf(x0, w.x, a0.x); a0.y = fmaf(x0, w.y, a0.y);
        a0.z = fmaf(x0, w.z, a0.z); a0.w = fmaf(x0, w.w, a0.w);
        a1.x = fmaf(x1, w.x, a1.x); a1.y = fmaf(x1, w.y, a1.y);
        a1.z = fmaf(x1, w.z, a1.z); a1.w = fmaf(x1, w.w, a1.w);
    }
    *(float4*)(Y + (size_t)(node0 + n0) * 128 + ftile + tx * 4) = a0;
    *(float4*)(Y + (size_t)(node0 + n1) * 128 + ftile + tx * 4) = a1;
}

__global__ __launch_bounds__(256) void gemm40_kernel(const float* __restrict__ X,
        const float* __restrict__ W, const float* __restrict__ sc,
        float* __restrict__ Y) {
    __shared__ float Ws[128][40];
    __shared__ float Xs[32][132];
    int tx = threadIdx.x, ty = threadIdx.y;
    int tid = ty * 8 + tx;
    int node0 = blockIdx.x * 32;

    float* wf = &Ws[0][0];
    for (int idx = tid; idx < 128 * 40; idx += 256) wf[idx] = W[idx];
    for (int idx = tid * 4; idx < 32 * 128; idx += 256 * 4) {
        int n = idx >> 7, f = idx & 127;
        float4 v = *(const float4*)(X + (size_t)(node0 + n) * 128 + f);
        v.x = fmaxf(fmaf(v.x, sc[f],     sc[128 + f]),     0.f);
        v.y = fmaxf(fmaf(v.y, sc[f + 1], sc[128 + f + 1]), 0.f);
        v.z = fmaxf(fmaf(v.z, sc[f + 2], sc[128 + f + 2]), 0.f);
        v.w = fmaxf(fmaf(v.w, sc[f + 3], sc[128 + f + 3]), 0.f);
        *(float4*)&Xs[n][f] = v;
    }
    __syncthreads();

    float acc[5] = {0,0,0,0,0};
    int f0 = tx * 5;
    #pragma unroll 4
    for (int k = 0; k < 128; ++k) {
        float xv = Xs[ty][k];
        #pragma unroll
        for (int j = 0; j < 5; ++j) acc[j] = fmaf(xv, Ws[k][f0 + j], acc[j]);
    }
    float* yp = Y + (size_t)(node0 + ty) * 40 + f0;
    #pragma unroll
    for (int j = 0; j < 5; ++j) yp[j] = acc[j];
}

// ---------------- aggregation ----------------
__global__ __launch_bounds__(256) void agg128_kernel(const float* __restrict__ H,
        const int* __restrict__ rowptr, const int* __restrict__ srcs,
        const float* __restrict__ dinv, const float* __restrict__ bias,
        float* __restrict__ out) {
    int wave = threadIdx.x >> 6;
    int lane = threadIdx.x & 63;
    int node = blockIdx.x * 4 + wave;
    int beg = rowptr[node], end = rowptr[node + 1];
    int c = lane * 2;
    float a0 = 0.f, a1 = 0.f;
    int e = beg;
    for (; e + 1 < end; e += 2) {
        int s0 = srcs[e], s1 = srcs[e + 1];
        float w0 = dinv[s0], w1 = dinv[s1];
        float2 h0 = *(const float2*)(H + (size_t)s0 * 128 + c);
        float2 h1 = *(const float2*)(H + (size_t)s1 * 128 + c);
        a0 = fmaf(w0, h0.x, a0); a1 = fmaf(w0, h0.y, a1);
        a0 = fmaf(w1, h1.x, a0); a1 = fmaf(w1, h1.y, a1);
    }
    if (e < end) {
        int s = srcs[e];
        float w = dinv[s];
        float2 h = *(const float2*)(H + (size_t)s * 128 + c);
        a0 = fmaf(w, h.x, a0); a1 = fmaf(w, h.y, a1);
    }
    float di = dinv[node];
    float2 hs = *(const float2*)(H + (size_t)node * 128 + c);
    a0 = di * (a0 + di * hs.x) + bias[c];
    a1 = di * (a1 + di * hs.y) + bias[c + 1];
    *(float2*)(out + (size_t)node * 128 + c) = make_float2(a0, a1);
}

__global__ __launch_bounds__(256) void agg40_softmax_kernel(const float* __restrict__ H,
        const int* __restrict__ rowptr, const int* __restrict__ srcs,
        const float* __restrict__ dinv, const float* __restrict__ bias,
        float* __restrict__ out) {
    int wave = threadIdx.x >> 6;
    int lane = threadIdx.x & 63;
    int node = blockIdx.x * 4 + wave;
    int beg = rowptr[node], end = rowptr[node + 1];
    bool act = lane < 40;
    float a = 0.f;
    for (int e = beg; e < end; ++e) {
        int s = srcs[e];
        float w = dinv[s];
        float h = act ? H[(size_t)s * 40 + lane] : 0.f;
        a = fmaf(w, h, a);
    }
    float di = dinv[node];
    float v = -3.0e38f;
    if (act) {
        float hs = H[(size_t)node * 40 + lane];
        v = di * (a + di * hs) + bias[lane];
    }
    float m = v;
    #pragma unroll
    for (int off = 32; off > 0; off >>= 1) m = fmaxf(m, __shfl_xor(m, off));
    float ev = act ? expf(v - m) : 0.f;
    float ssum = ev;
    #pragma unroll
    for (int off = 32; off > 0; off >>= 1) ssum += __shfl_xor(ssum, off);
    if (act) out[(size_t)node * 40 + lane] = ev / ssum;
}

// ---------------- launch ----------------

extern "C" void kernel_launch(void* const* d_in, const int* in_sizes, int n_in,
                              void* d_out, int out_size, void* d_ws, size_t ws_size,
                              hipStream_t stream) {
    const float* x   = (const float*)d_in[0];
    const int*   ei  = (const int*)d_in[1];
    const float* W1  = (const float*)d_in[2];
    const float* b1  = (const float*)d_in[3];
    const float* g1  = (const float*)d_in[4];
    const float* be1 = (const float*)d_in[5];
    const float* W2  = (const float*)d_in[6];
    const float* b2  = (const float*)d_in[7];
    const float* g2  = (const float*)d_in[8];
    const float* be2 = (const float*)d_in[9];
    const float* W3  = (const float*)d_in[10];
    const float* b3  = (const float*)d_in[11];
    float* out = (float*)d_out;
    const int* src = ei;
    const int* dst = ei + NE;

    char* p = (char*)d_ws;
    auto alloc = [&](size_t bytes) { char* r = p; p += (bytes + 255) & ~255ull; return r; };
    int*   cnt       = (int*)  alloc((size_t)NN * 4);
    int*   rowptr    = (int*)  alloc((size_t)(NN + 1) * 4);
    int*   cursor    = (int*)  alloc((size_t)NN * 4);
    int*   srcsorted = (int*)  alloc((size_t)NE * 4);
    float* dinv      = (float*)alloc((size_t)NN * 4);
    float* stats     = (float*)alloc(256 * 4);
    float* sc        = (float*)alloc(256 * 4);
    int*   blocksum  = (int*)  alloc((size_t)NBLK * 4);
    int*   blockoff  = (int*)  alloc((size_t)NBLK * 4);
    float* A         = (float*)alloc((size_t)NN * 128 * 4);
    float* B         = (float*)alloc((size_t)NN * 128 * 4);

    hipMemsetAsync(cnt, 0, (size_t)NN * 4, stream);
    count_kernel<<<NE / 256, 256, 0, stream>>>(dst, cnt);
    dinv_kernel<<<(NN + 255) / 256, 256, 0, stream>>>(cnt, dinv);
    scan1_kernel<<<NBLK, 256, 0, stream>>>(cnt, blocksum);
    scan2_kernel<<<1, 256, 0, stream>>>(blocksum, blockoff, rowptr + NN);
    scan3_kernel<<<NBLK, 256, 0, stream>>>(cnt, blockoff, rowptr, cursor);
    fill_kernel<<<NE / 256, 256, 0, stream>>>(src, dst, cursor, srcsorted);

    dim3 gb(16, 16);
    // layer 1
    gemm128_kernel<false><<<dim3(NN / 32, 2), gb, 0, stream>>>(x, W1, nullptr, A);
    agg128_kernel<<<NN / 4, 256, 0, stream>>>(A, rowptr, srcsorted, dinv, b1, B);
    hipMemsetAsync(stats, 0, 256 * 4, stream);
    bnstats_kernel<<<1024, 256, 0, stream>>>(B, stats);
    bnfinal_kernel<<<1, 128, 0, stream>>>(stats, g1, be1, sc);
    // layer 2 (BN+ReLU fused into GEMM X-load)
    gemm128_kernel<true><<<dim3(NN / 32, 2), gb, 0, stream>>>(B, W2, sc, A);
    agg128_kernel<<<NN / 4, 256, 0, stream>>>(A, rowptr, srcsorted, dinv, b2, B);
    hipMemsetAsync(stats, 0, 256 * 4, stream);
    bnstats_kernel<<<1024, 256, 0, stream>>>(B, stats);
    bnfinal_kernel<<<1, 128, 0, stream>>>(stats, g2, be2, sc);
    // layer 3 (BN+ReLU fused) + aggregation + softmax fused
    gemm40_kernel<<<dim3(NN / 32), dim3(8, 32), 0, stream>>>(B, W3, sc, A);
    agg40_softmax_kernel<<<NN / 4, 256, 0, stream>>>(A, rowptr, srcsorted, dinv, b3, out);
}

// Round 3
// 831.283 us; speedup vs baseline: 1.3984x; 1.1546x over previous
//
#include <hip/hip_runtime.h>
#include <hip/hip_bf16.h>

#define NN   100000
#define NE   1600000
#define FHID 128
#define FO3  40
#define SCAN_CHUNK 512
#define NBLK ((NN + SCAN_CHUNK - 1) / SCAN_CHUNK)   // 196
constexpr float EPSV = 1e-5f;

// ---------------- graph prep ----------------

__global__ void count_kernel(const int* __restrict__ dst, int* __restrict__ cnt) {
    int e = blockIdx.x * 256 + threadIdx.x;
    if (e < NE) atomicAdd(&cnt[dst[e]], 1);
}

__global__ void dinv_kernel(const int* __restrict__ cnt, float* __restrict__ dinv) {
    int i = blockIdx.x * 256 + threadIdx.x;
    if (i < NN) dinv[i] = rsqrtf((float)cnt[i] + 1.0f);   // +1 = self loop
}

__global__ __launch_bounds__(256) void scan1_kernel(const int* __restrict__ cnt,
                                                    int* __restrict__ blocksum) {
    __shared__ int red[256];
    int t = threadIdx.x;
    int base = blockIdx.x * SCAN_CHUNK + t * 2;
    int v = 0;
    if (base < NN)     v += cnt[base];
    if (base + 1 < NN) v += cnt[base + 1];
    red[t] = v;
    __syncthreads();
    #pragma unroll
    for (int off = 128; off > 0; off >>= 1) {
        if (t < off) red[t] += red[t + off];
        __syncthreads();
    }
    if (t == 0) blocksum[blockIdx.x] = red[0];
}

__global__ __launch_bounds__(256) void scan2_kernel(const int* __restrict__ blocksum,
                                                    int* __restrict__ blockoff,
                                                    int* __restrict__ rowptr_end) {
    __shared__ int s[256];
    int t = threadIdx.x;
    int v = (t < NBLK) ? blocksum[t] : 0;
    s[t] = v;
    __syncthreads();
    #pragma unroll
    for (int off = 1; off < 256; off <<= 1) {
        int u = (t >= off) ? s[t - off] : 0;
        __syncthreads();
        s[t] += u;
        __syncthreads();
    }
    if (t < NBLK) blockoff[t] = s[t] - v;   // exclusive
    if (t == 255) rowptr_end[0] = s[255];
}

__global__ __launch_bounds__(256) void scan3_kernel(const int* __restrict__ cnt,
                                                    const int* __restrict__ blockoff,
                                                    int* __restrict__ rowptr,
                                                    int* __restrict__ cursor) {
    __shared__ int s[256];
    int t = threadIdx.x;
    int base = blockIdx.x * SCAN_CHUNK + t * 2;
    int c0 = (base < NN) ? cnt[base] : 0;
    int c1 = (base + 1 < NN) ? cnt[base + 1] : 0;
    int pair = c0 + c1;
    s[t] = pair;
    __syncthreads();
    #pragma unroll
    for (int off = 1; off < 256; off <<= 1) {
        int u = (t >= off) ? s[t - off] : 0;
        __syncthreads();
        s[t] += u;
        __syncthreads();
    }
    int excl = blockoff[blockIdx.x] + s[t] - pair;
    if (base < NN)     { rowptr[base] = excl;          cursor[base] = excl; }
    if (base + 1 < NN) { rowptr[base + 1] = excl + c0; cursor[base + 1] = excl + c0; }
}

__global__ void fill_kernel(const int* __restrict__ src, const int* __restrict__ dst,
                            int* __restrict__ cursor, int* __restrict__ srcsorted) {
    int e = blockIdx.x * 256 + threadIdx.x;
    if (e < NE) {
        int d = dst[e];
        int pos = atomicAdd(&cursor[d], 1);
        srcsorted[pos] = src[e];
    }
}

// ---------------- batchnorm stats ----------------

__global__ void bnstats_kernel(const float* __restrict__ X, float* __restrict__ stats) {
    int f = threadIdx.x & 127;
    int rg = threadIdx.x >> 7;
    float s = 0.f, s2 = 0.f;
    for (int r = blockIdx.x * 2 + rg; r < NN; r += gridDim.x * 2) {
        float v = X[(size_t)r * 128 + f];
        s += v; s2 += v * v;
    }
    atomicAdd(&stats[f], s);
    atomicAdd(&stats[128 + f], s2);
}

__global__ void bnfinal_kernel(const float* __restrict__ stats, const float* __restrict__ g,
                               const float* __restrict__ be, float* __restrict__ sc) {
    int f = threadIdx.x;
    float mu  = stats[f] * (1.0f / NN);
    float var = stats[128 + f] * (1.0f / NN) - mu * mu;
    float rstd = rsqrtf(var + EPSV);
    float scale = g[f] * rstd;
    sc[f]       = scale;
    sc[128 + f] = be[f] - mu * scale;
}

// ---------------- dense GEMMs (epilogue: scale row by dinv[row]) ----------------
template<bool BN>
__global__ __launch_bounds__(256) void gemm128_kernel(const float* __restrict__ X,
        const float* __restrict__ W, const float* __restrict__ sc,
        const float* __restrict__ dinv, float* __restrict__ Y) {
    __shared__ float Ws[128][64];
    __shared__ float Xs[32][132];
    int tx = threadIdx.x, ty = threadIdx.y;
    int tid = ty * 16 + tx;
    int ftile = blockIdx.y * 64;
    int node0 = blockIdx.x * 32;

    for (int idx = tid * 4; idx < 128 * 64; idx += 256 * 4) {
        int k = idx >> 6, c = idx & 63;
        float4 w4 = *(const float4*)(W + (size_t)k * 128 + ftile + c);
        *(float4*)&Ws[k][c] = w4;
    }
    for (int idx = tid * 4; idx < 32 * 128; idx += 256 * 4) {
        int n = idx >> 7, f = idx & 127;
        float4 v = *(const float4*)(X + (size_t)(node0 + n) * 128 + f);
        if constexpr (BN) {
            v.x = fmaxf(fmaf(v.x, sc[f],     sc[128 + f]),     0.f);
            v.y = fmaxf(fmaf(v.y, sc[f + 1], sc[128 + f + 1]), 0.f);
            v.z = fmaxf(fmaf(v.z, sc[f + 2], sc[128 + f + 2]), 0.f);
            v.w = fmaxf(fmaf(v.w, sc[f + 3], sc[128 + f + 3]), 0.f);
        }
        *(float4*)&Xs[n][f] = v;
    }
    __syncthreads();

    float4 a0 = {0,0,0,0}, a1 = {0,0,0,0};
    int n0 = ty, n1 = ty + 16;
    #pragma unroll 4
    for (int k = 0; k < 128; ++k) {
        float4 w = *(float4*)&Ws[k][tx * 4];
        float x0 = Xs[n0][k];
        float x1 = Xs[n1][k];
        a0.x = fmaf(x0, w.x, a0.x); a0.y = fmaf(x0, w.y, a0.y);
        a0.z = fmaf(x0, w.z, a0.z); a0.w = fmaf(x0, w.w, a0.w);
        a1.x = fmaf(x1, w.x, a1.x); a1.y = fmaf(x1, w.y, a1.y);
        a1.z = fmaf(x1, w.z, a1.z); a1.w = fmaf(x1, w.w, a1.w);
    }
    float di0 = dinv[node0 + n0], di1 = dinv[node0 + n1];
    a0.x *= di0; a0.y *= di0; a0.z *= di0; a0.w *= di0;
    a1.x *= di1; a1.y *= di1; a1.z *= di1; a1.w *= di1;
    *(float4*)(Y + (size_t)(node0 + n0) * 128 + ftile + tx * 4) = a0;
    *(float4*)(Y + (size_t)(node0 + n1) * 128 + ftile + tx * 4) = a1;
}

__global__ __launch_bounds__(256) void gemm40_kernel(const float* __restrict__ X,
        const float* __restrict__ W, const float* __restrict__ sc,
        const float* __restrict__ dinv, float* __restrict__ Y) {
    __shared__ float Ws[128][40];
    __shared__ float Xs[32][132];
    int tx = threadIdx.x, ty = threadIdx.y;
    int tid = ty * 8 + tx;
    int node0 = blockIdx.x * 32;

    float* wf = &Ws[0][0];
    for (int idx = tid; idx < 128 * 40; idx += 256) wf[idx] = W[idx];
    for (int idx = tid * 4; idx < 32 * 128; idx += 256 * 4) {
        int n = idx >> 7, f = idx & 127;
        float4 v = *(const float4*)(X + (size_t)(node0 + n) * 128 + f);
        v.x = fmaxf(fmaf(v.x, sc[f],     sc[128 + f]),     0.f);
        v.y = fmaxf(fmaf(v.y, sc[f + 1], sc[128 + f + 1]), 0.f);
        v.z = fmaxf(fmaf(v.z, sc[f + 2], sc[128 + f + 2]), 0.f);
        v.w = fmaxf(fmaf(v.w, sc[f + 3], sc[128 + f + 3]), 0.f);
        *(float4*)&Xs[n][f] = v;
    }
    __syncthreads();

    float acc[5] = {0,0,0,0,0};
    int f0 = tx * 5;
    #pragma unroll 4
    for (int k = 0; k < 128; ++k) {
        float xv = Xs[ty][k];
        #pragma unroll
        for (int j = 0; j < 5; ++j) acc[j] = fmaf(xv, Ws[k][f0 + j], acc[j]);
    }
    float di = dinv[node0 + ty];
    float* yp = Y + (size_t)(node0 + ty) * 40 + f0;
    #pragma unroll
    for (int j = 0; j < 5; ++j) yp[j] = acc[j] * di;
}

// ---------------- aggregation (H rows pre-scaled by dinv[src]) ----------------
// one wave per node, 2 feats/lane, 4 edges in flight
__global__ __launch_bounds__(256) void agg128_kernel(const float* __restrict__ H,
        const int* __restrict__ rowptr, const int* __restrict__ srcs,
        const float* __restrict__ dinv, const float* __restrict__ bias,
        float* __restrict__ out) {
    int wave = threadIdx.x >> 6;
    int lane = threadIdx.x & 63;
    int node = blockIdx.x * 4 + wave;
    int beg = rowptr[node], end = rowptr[node + 1];
    int c = lane * 2;
    float a0 = 0.f, a1 = 0.f, b0 = 0.f, b1 = 0.f;
    int e = beg;
    for (; e + 3 < end; e += 4) {
        int s0 = srcs[e], s1 = srcs[e + 1], s2 = srcs[e + 2], s3 = srcs[e + 3];
        float2 h0 = *(const float2*)(H + (size_t)s0 * 128 + c);
        float2 h1 = *(const float2*)(H + (size_t)s1 * 128 + c);
        float2 h2 = *(const float2*)(H + (size_t)s2 * 128 + c);
        float2 h3 = *(const float2*)(H + (size_t)s3 * 128 + c);
        a0 += h0.x + h1.x; a1 += h0.y + h1.y;
        b0 += h2.x + h3.x; b1 += h2.y + h3.y;
    }
    for (; e < end; ++e) {
        int s = srcs[e];
        float2 h = *(const float2*)(H + (size_t)s * 128 + c);
        a0 += h.x; a1 += h.y;
    }
    float di = dinv[node];
    float2 hs = *(const float2*)(H + (size_t)node * 128 + c);   // already * dinv[node]
    a0 = di * (a0 + b0 + hs.x) + bias[c];
    a1 = di * (a1 + b1 + hs.y) + bias[c + 1];
    *(float2*)(out + (size_t)node * 128 + c) = make_float2(a0, a1);
}

// final: aggregate 40 feats + bias + softmax, 4 edges in flight
__global__ __launch_bounds__(256) void agg40_softmax_kernel(const float* __restrict__ H,
        const int* __restrict__ rowptr, const int* __restrict__ srcs,
        const float* __restrict__ dinv, const float* __restrict__ bias,
        float* __restrict__ out) {
    int wave = threadIdx.x >> 6;
    int lane = threadIdx.x & 63;
    int node = blockIdx.x * 4 + wave;
    int beg = rowptr[node], end = rowptr[node + 1];
    bool act = lane < 40;
    int ln = act ? lane : 0;
    float a0 = 0.f, a1 = 0.f, a2 = 0.f, a3 = 0.f;
    int e = beg;
    for (; e + 3 < end; e += 4) {
        int s0 = srcs[e], s1 = srcs[e + 1], s2 = srcs[e + 2], s3 = srcs[e + 3];
        a0 += H[(size_t)s0 * 40 + ln];
        a1 += H[(size_t)s1 * 40 + ln];
        a2 += H[(size_t)s2 * 40 + ln];
        a3 += H[(size_t)s3 * 40 + ln];
    }
    for (; e < end; ++e) a0 += H[(size_t)srcs[e] * 40 + ln];
    float di = dinv[node];
    float hs = H[(size_t)node * 40 + ln];
    float v = act ? (di * (a0 + a1 + a2 + a3 + hs) + bias[ln]) : -3.0e38f;
    float m = v;
    #pragma unroll
    for (int off = 32; off > 0; off >>= 1) m = fmaxf(m, __shfl_xor(m, off));
    float ev = act ? expf(v - m) : 0.f;
    float ssum = ev;
    #pragma unroll
    for (int off = 32; off > 0; off >>= 1) ssum += __shfl_xor(ssum, off);
    if (act) out[(size_t)node * 40 + lane] = ev / ssum;
}

// ---------------- launch ----------------

extern "C" void kernel_launch(void* const* d_in, const int* in_sizes, int n_in,
                              void* d_out, int out_size, void* d_ws, size_t ws_size,
                              hipStream_t stream) {
    const float* x   = (const float*)d_in[0];
    const int*   ei  = (const int*)d_in[1];
    const float* W1  = (const float*)d_in[2];
    const float* b1  = (const float*)d_in[3];
    const float* g1  = (const float*)d_in[4];
    const float* be1 = (const float*)d_in[5];
    const float* W2  = (const float*)d_in[6];
    const float* b2  = (const float*)d_in[7];
    const float* g2  = (const float*)d_in[8];
    const float* be2 = (const float*)d_in[9];
    const float* W3  = (const float*)d_in[10];
    const float* b3  = (const float*)d_in[11];
    float* out = (float*)d_out;
    const int* src = ei;
    const int* dst = ei + NE;

    char* p = (char*)d_ws;
    auto alloc = [&](size_t bytes) { char* r = p; p += (bytes + 255) & ~255ull; return r; };
    int*   cnt       = (int*)  alloc((size_t)NN * 4);
    int*   rowptr    = (int*)  alloc((size_t)(NN + 1) * 4);
    int*   cursor    = (int*)  alloc((size_t)NN * 4);
    int*   srcsorted = (int*)  alloc((size_t)NE * 4);
    float* dinv      = (float*)alloc((size_t)NN * 4);
    float* stats     = (float*)alloc(256 * 4);
    float* sc        = (float*)alloc(256 * 4);
    int*   blocksum  = (int*)  alloc((size_t)NBLK * 4);
    int*   blockoff  = (int*)  alloc((size_t)NBLK * 4);
    float* A         = (float*)alloc((size_t)NN * 128 * 4);
    float* B         = (float*)alloc((size_t)NN * 128 * 4);

    hipMemsetAsync(cnt, 0, (size_t)NN * 4, stream);
    count_kernel<<<NE / 256, 256, 0, stream>>>(dst, cnt);
    dinv_kernel<<<(NN + 255) / 256, 256, 0, stream>>>(cnt, dinv);
    scan1_kernel<<<NBLK, 256, 0, stream>>>(cnt, blocksum);
    scan2_kernel<<<1, 256, 0, stream>>>(blocksum, blockoff, rowptr + NN);
    scan3_kernel<<<NBLK, 256, 0, stream>>>(cnt, blockoff, rowptr, cursor);
    fill_kernel<<<NE / 256, 256, 0, stream>>>(src, dst, cursor, srcsorted);

    dim3 gb(16, 16);
    // layer 1
    gemm128_kernel<false><<<dim3(NN / 32, 2), gb, 0, stream>>>(x, W1, nullptr, dinv, A);
    agg128_kernel<<<NN / 4, 256, 0, stream>>>(A, rowptr, srcsorted, dinv, b1, B);
    hipMemsetAsync(stats, 0, 256 * 4, stream);
    bnstats_kernel<<<1024, 256, 0, stream>>>(B, stats);
    bnfinal_kernel<<<1, 128, 0, stream>>>(stats, g1, be1, sc);
    // layer 2
    gemm128_kernel<true><<<dim3(NN / 32, 2), gb, 0, stream>>>(B, W2, sc, dinv, A);
    agg128_kernel<<<NN / 4, 256, 0, stream>>>(A, rowptr, srcsorted, dinv, b2, B);
    hipMemsetAsync(stats, 0, 256 * 4, stream);
    bnstats_kernel<<<1024, 256, 0, stream>>>(B, stats);
    bnfinal_kernel<<<1, 128, 0, stream>>>(stats, g2, be2, sc);
    // layer 3
    gemm40_kernel<<<dim3(NN / 32), dim3(8, 32), 0, stream>>>(B, W3, sc, dinv, A);
    agg40_softmax_kernel<<<NN / 4, 256, 0, stream>>>(A, rowptr, srcsorted, dinv, b3, out);
}

// Round 4
// 745.741 us; speedup vs baseline: 1.5588x; 1.1147x over previous
//
#include <hip/hip_runtime.h>
#include <hip/hip_bf16.h>

#define NN   100000
#define NE   1600000
#define FHID 128
#define FO3  40
#define NBUCK 391                 // ceil(NN/256) buckets of 256 nodes
#define NW1   64                  // pass-1 workgroups
#define CH1   (NE / NW1)          // 25000 edges per pass-1 wg
#define GN    (NBUCK * NW1)       // 25024 scan entries
constexpr float EPSV = 1e-5f;

// ---------------- graph prep: 2-level bucket CSR build ----------------
// P1: partition edges into 391 buckets by dst>>8 (wg-local 256B runs -> low write amp)
// P2: per-bucket exact CSR in a 16KB XCD-local window (no cross-XCD line ping-pong)

__global__ __launch_bounds__(256) void p1hist_kernel(const int* __restrict__ dst,
                                                     int* __restrict__ G) {
    __shared__ int h[NBUCK];
    int t = threadIdx.x, wg = blockIdx.x;
    for (int i = t; i < NBUCK; i += 256) h[i] = 0;
    __syncthreads();
    int base = wg * CH1;
    for (int e = base + t; e < base + CH1; e += 256)
        atomicAdd(&h[dst[e] >> 8], 1);
    __syncthreads();
    for (int i = t; i < NBUCK; i += 256) G[i * NW1 + wg] = h[i];
}

__global__ __launch_bounds__(1024) void p1scan_kernel(int* __restrict__ G) {
    __shared__ int s[1024];
    const int C = (GN + 1023) / 1024;   // 25
    int t = threadIdx.x;
    int b0 = t * C, b1 = b0 + C; if (b1 > GN) b1 = GN;
    int loc = 0;
    for (int i = b0; i < b1; ++i) loc += G[i];
    s[t] = loc;
    __syncthreads();
    #pragma unroll
    for (int off = 1; off < 1024; off <<= 1) {
        int u = (t >= off) ? s[t - off] : 0;
        __syncthreads();
        s[t] += u;
        __syncthreads();
    }
    int run = (t == 0) ? 0 : s[t - 1];
    for (int i = b0; i < b1; ++i) { int v = G[i]; G[i] = run; run += v; }
}

__global__ __launch_bounds__(256) void p1fill_kernel(const int* __restrict__ src,
                                                     const int* __restrict__ dst,
                                                     const int* __restrict__ G,
                                                     int* __restrict__ ebuf) {
    __shared__ int cur[NBUCK];
    int t = threadIdx.x, wg = blockIdx.x;
    for (int i = t; i < NBUCK; i += 256) cur[i] = G[i * NW1 + wg];
    __syncthreads();
    int base = wg * CH1;
    for (int e = base + t; e < base + CH1; e += 256) {
        int d = dst[e];
        int pos = atomicAdd(&cur[d >> 8], 1);
        ebuf[pos] = src[e] | ((d & 255) << 17);   // src<2^17, pack low dst byte
    }
}

__global__ __launch_bounds__(256) void p2build_kernel(const int* __restrict__ ebuf,
                                                      const int* __restrict__ G,
                                                      int* __restrict__ rowptr,
                                                      int* __restrict__ srcsorted,
                                                      float* __restrict__ dinv) {
    __shared__ int cnt[256];
    __shared__ int s[256];
    __shared__ int cur[256];
    int t = threadIdx.x, b = blockIdx.x;
    int base = G[b * NW1];
    int endp = (b == NBUCK - 1) ? NE : G[(b + 1) * NW1];
    cnt[t] = 0;
    __syncthreads();
    for (int e = base + t; e < endp; e += 256)
        atomicAdd(&cnt[ebuf[e] >> 17], 1);
    __syncthreads();
    int c = cnt[t];
    s[t] = c;
    __syncthreads();
    #pragma unroll
    for (int off = 1; off < 256; off <<= 1) {
        int u = (t >= off) ? s[t - off] : 0;
        __syncthreads();
        s[t] += u;
        __syncthreads();
    }
    int excl = s[t] - c;
    int node = b * 256 + t;
    if (node < NN) {
        rowptr[node] = base + excl;
        dinv[node]   = rsqrtf((float)c + 1.0f);   // +1 self loop
    }
    cur[t] = base + excl;
    __syncthreads();
    for (int e = base + t; e < endp; e += 256) {
        int p = ebuf[e];
        int pos = atomicAdd(&cur[p >> 17], 1);
        srcsorted[pos] = p & 0x1FFFF;
    }
    if (b == NBUCK - 1 && t == 0) rowptr[NN] = NE;
}

// ---------------- batchnorm stats ----------------

__global__ void bnstats_kernel(const float* __restrict__ X, float* __restrict__ stats) {
    int f = threadIdx.x & 127;
    int rg = threadIdx.x >> 7;
    float s = 0.f, s2 = 0.f;
    for (int r = blockIdx.x * 2 + rg; r < NN; r += gridDim.x * 2) {
        float v = X[(size_t)r * 128 + f];
        s += v; s2 += v * v;
    }
    atomicAdd(&stats[f], s);
    atomicAdd(&stats[128 + f], s2);
}

__global__ void bnfinal_kernel(const float* __restrict__ stats, const float* __restrict__ g,
                               const float* __restrict__ be, float* __restrict__ sc) {
    int f = threadIdx.x;
    float mu  = stats[f] * (1.0f / NN);
    float var = stats[128 + f] * (1.0f / NN) - mu * mu;
    float rstd = rsqrtf(var + EPSV);
    float scale = g[f] * rstd;
    sc[f]       = scale;
    sc[128 + f] = be[f] - mu * scale;
}

// ---------------- dense GEMMs (epilogue: scale row by dinv[row]) ----------------
template<bool BN>
__global__ __launch_bounds__(256) void gemm128_kernel(const float* __restrict__ X,
        const float* __restrict__ W, const float* __restrict__ sc,
        const float* __restrict__ dinv, float* __restrict__ Y) {
    __shared__ float Ws[128][64];
    __shared__ float Xs[32][132];
    int tx = threadIdx.x, ty = threadIdx.y;
    int tid = ty * 16 + tx;
    int ftile = blockIdx.y * 64;
    int node0 = blockIdx.x * 32;

    for (int idx = tid * 4; idx < 128 * 64; idx += 256 * 4) {
        int k = idx >> 6, c = idx & 63;
        float4 w4 = *(const float4*)(W + (size_t)k * 128 + ftile + c);
        *(float4*)&Ws[k][c] = w4;
    }
    for (int idx = tid * 4; idx < 32 * 128; idx += 256 * 4) {
        int n = idx >> 7, f = idx & 127;
        float4 v = *(const float4*)(X + (size_t)(node0 + n) * 128 + f);
        if constexpr (BN) {
            v.x = fmaxf(fmaf(v.x, sc[f],     sc[128 + f]),     0.f);
            v.y = fmaxf(fmaf(v.y, sc[f + 1], sc[128 + f + 1]), 0.f);
            v.z = fmaxf(fmaf(v.z, sc[f + 2], sc[128 + f + 2]), 0.f);
            v.w = fmaxf(fmaf(v.w, sc[f + 3], sc[128 + f + 3]), 0.f);
        }
        *(float4*)&Xs[n][f] = v;
    }
    __syncthreads();

    float4 a0 = {0,0,0,0}, a1 = {0,0,0,0};
    int n0 = ty, n1 = ty + 16;
    #pragma unroll 4
    for (int k = 0; k < 128; ++k) {
        float4 w = *(float4*)&Ws[k][tx * 4];
        float x0 = Xs[n0][k];
        float x1 = Xs[n1][k];
        a0.x = fmaf(x0, w.x, a0.x); a0.y = fmaf(x0, w.y, a0.y);
        a0.z = fmaf(x0, w.z, a0.z); a0.w = fmaf(x0, w.w, a0.w);
        a1.x = fmaf(x1, w.x, a1.x); a1.y = fmaf(x1, w.y, a1.y);
        a1.z = fmaf(x1, w.z, a1.z); a1.w = fmaf(x1, w.w, a1.w);
    }
    float di0 = dinv[node0 + n0], di1 = dinv[node0 + n1];
    a0.x *= di0; a0.y *= di0; a0.z *= di0; a0.w *= di0;
    a1.x *= di1; a1.y *= di1; a1.z *= di1; a1.w *= di1;
    *(float4*)(Y + (size_t)(node0 + n0) * 128 + ftile + tx * 4) = a0;
    *(float4*)(Y + (size_t)(node0 + n1) * 128 + ftile + tx * 4) = a1;
}

__global__ __launch_bounds__(256) void gemm40_kernel(const float* __restrict__ X,
        const float* __restrict__ W, const float* __restrict__ sc,
        const float* __restrict__ dinv, float* __restrict__ Y) {
    __shared__ float Ws[128][40];
    __shared__ float Xs[32][132];
    int tx = threadIdx.x, ty = threadIdx.y;
    int tid = ty * 8 + tx;
    int node0 = blockIdx.x * 32;

    float* wf = &Ws[0][0];
    for (int idx = tid; idx < 128 * 40; idx += 256) wf[idx] = W[idx];
    for (int idx = tid * 4; idx < 32 * 128; idx += 256 * 4) {
        int n = idx >> 7, f = idx & 127;
        float4 v = *(const float4*)(X + (size_t)(node0 + n) * 128 + f);
        v.x = fmaxf(fmaf(v.x, sc[f],     sc[128 + f]),     0.f);
        v.y = fmaxf(fmaf(v.y, sc[f + 1], sc[128 + f + 1]), 0.f);
        v.z = fmaxf(fmaf(v.z, sc[f + 2], sc[128 + f + 2]), 0.f);
        v.w = fmaxf(fmaf(v.w, sc[f + 3], sc[128 + f + 3]), 0.f);
        *(float4*)&Xs[n][f] = v;
    }
    __syncthreads();

    float acc[5] = {0,0,0,0,0};
    int f0 = tx * 5;
    #pragma unroll 4
    for (int k = 0; k < 128; ++k) {
        float xv = Xs[ty][k];
        #pragma unroll
        for (int j = 0; j < 5; ++j) acc[j] = fmaf(xv, Ws[k][f0 + j], acc[j]);
    }
    float di = dinv[node0 + ty];
    float* yp = Y + (size_t)(node0 + ty) * 40 + f0;
    #pragma unroll
    for (int j = 0; j < 5; ++j) yp[j] = acc[j] * di;
}

// ---------------- aggregation (H rows pre-scaled by dinv[src]) ----------------
__global__ __launch_bounds__(256) void agg128_kernel(const float* __restrict__ H,
        const int* __restrict__ rowptr, const int* __restrict__ srcs,
        const float* __restrict__ dinv, const float* __restrict__ bias,
        float* __restrict__ out) {
    int wave = threadIdx.x >> 6;
    int lane = threadIdx.x & 63;
    int node = blockIdx.x * 4 + wave;
    int beg = rowptr[node], end = rowptr[node + 1];
    int c = lane * 2;
    float a0 = 0.f, a1 = 0.f, b0 = 0.f, b1 = 0.f;
    int e = beg;
    for (; e + 3 < end; e += 4) {
        int s0 = srcs[e], s1 = srcs[e + 1], s2 = srcs[e + 2], s3 = srcs[e + 3];
        float2 h0 = *(const float2*)(H + (size_t)s0 * 128 + c);
        float2 h1 = *(const float2*)(H + (size_t)s1 * 128 + c);
        float2 h2 = *(const float2*)(H + (size_t)s2 * 128 + c);
        float2 h3 = *(const float2*)(H + (size_t)s3 * 128 + c);
        a0 += h0.x + h1.x; a1 += h0.y + h1.y;
        b0 += h2.x + h3.x; b1 += h2.y + h3.y;
    }
    for (; e < end; ++e) {
        int s = srcs[e];
        float2 h = *(const float2*)(H + (size_t)s * 128 + c);
        a0 += h.x; a1 += h.y;
    }
    float di = dinv[node];
    float2 hs = *(const float2*)(H + (size_t)node * 128 + c);
    a0 = di * (a0 + b0 + hs.x) + bias[c];
    a1 = di * (a1 + b1 + hs.y) + bias[c + 1];
    *(float2*)(out + (size_t)node * 128 + c) = make_float2(a0, a1);
}

__global__ __launch_bounds__(256) void agg40_softmax_kernel(const float* __restrict__ H,
        const int* __restrict__ rowptr, const int* __restrict__ srcs,
        const float* __restrict__ dinv, const float* __restrict__ bias,
        float* __restrict__ out) {
    int wave = threadIdx.x >> 6;
    int lane = threadIdx.x & 63;
    int node = blockIdx.x * 4 + wave;
    int beg = rowptr[node], end = rowptr[node + 1];
    bool act = lane < 40;
    int ln = act ? lane : 0;
    float a0 = 0.f, a1 = 0.f, a2 = 0.f, a3 = 0.f;
    int e = beg;
    for (; e + 3 < end; e += 4) {
        int s0 = srcs[e], s1 = srcs[e + 1], s2 = srcs[e + 2], s3 = srcs[e + 3];
        a0 += H[(size_t)s0 * 40 + ln];
        a1 += H[(size_t)s1 * 40 + ln];
        a2 += H[(size_t)s2 * 40 + ln];
        a3 += H[(size_t)s3 * 40 + ln];
    }
    for (; e < end; ++e) a0 += H[(size_t)srcs[e] * 40 + ln];
    float di = dinv[node];
    float hs = H[(size_t)node * 40 + ln];
    float v = act ? (di * (a0 + a1 + a2 + a3 + hs) + bias[ln]) : -3.0e38f;
    float m = v;
    #pragma unroll
    for (int off = 32; off > 0; off >>= 1) m = fmaxf(m, __shfl_xor(m, off));
    float ev = act ? expf(v - m) : 0.f;
    float ssum = ev;
    #pragma unroll
    for (int off = 32; off > 0; off >>= 1) ssum += __shfl_xor(ssum, off);
    if (act) out[(size_t)node * 40 + lane] = ev / ssum;
}

// ---------------- launch ----------------

extern "C" void kernel_launch(void* const* d_in, const int* in_sizes, int n_in,
                              void* d_out, int out_size, void* d_ws, size_t ws_size,
                              hipStream_t stream) {
    const float* x   = (const float*)d_in[0];
    const int*   ei  = (const int*)d_in[1];
    const float* W1  = (const float*)d_in[2];
    const float* b1  = (const float*)d_in[3];
    const float* g1  = (const float*)d_in[4];
    const float* be1 = (const float*)d_in[5];
    const float* W2  = (const float*)d_in[6];
    const float* b2  = (const float*)d_in[7];
    const float* g2  = (const float*)d_in[8];
    const float* be2 = (const float*)d_in[9];
    const float* W3  = (const float*)d_in[10];
    const float* b3  = (const float*)d_in[11];
    float* out = (float*)d_out;
    const int* src = ei;
    const int* dst = ei + NE;

    char* p = (char*)d_ws;
    auto alloc = [&](size_t bytes) { char* r = p; p += (bytes + 255) & ~255ull; return r; };
    int*   rowptr    = (int*)  alloc((size_t)(NN + 1) * 4);
    int*   srcsorted = (int*)  alloc((size_t)NE * 4);
    float* dinv      = (float*)alloc((size_t)NN * 4);
    float* stats     = (float*)alloc(256 * 4);
    float* sc        = (float*)alloc(256 * 4);
    int*   G         = (int*)  alloc((size_t)GN * 4);
    float* A         = (float*)alloc((size_t)NN * 128 * 4);
    float* B         = (float*)alloc((size_t)NN * 128 * 4);
    int*   ebuf      = (int*)A;   // A unused until layer-1 GEMM (after p2build)

    // graph prep
    p1hist_kernel<<<NW1, 256, 0, stream>>>(dst, G);
    p1scan_kernel<<<1, 1024, 0, stream>>>(G);
    p1fill_kernel<<<NW1, 256, 0, stream>>>(src, dst, G, ebuf);
    p2build_kernel<<<NBUCK, 256, 0, stream>>>(ebuf, G, rowptr, srcsorted, dinv);

    dim3 gb(16, 16);
    // layer 1
    gemm128_kernel<false><<<dim3(NN / 32, 2), gb, 0, stream>>>(x, W1, nullptr, dinv, A);
    agg128_kernel<<<NN / 4, 256, 0, stream>>>(A, rowptr, srcsorted, dinv, b1, B);
    hipMemsetAsync(stats, 0, 256 * 4, stream);
    bnstats_kernel<<<1024, 256, 0, stream>>>(B, stats);
    bnfinal_kernel<<<1, 128, 0, stream>>>(stats, g1, be1, sc);
    // layer 2
    gemm128_kernel<true><<<dim3(NN / 32, 2), gb, 0, stream>>>(B, W2, sc, dinv, A);
    agg128_kernel<<<NN / 4, 256, 0, stream>>>(A, rowptr, srcsorted, dinv, b2, B);
    hipMemsetAsync(stats, 0, 256 * 4, stream);
    bnstats_kernel<<<1024, 256, 0, stream>>>(B, stats);
    bnfinal_kernel<<<1, 128, 0, stream>>>(stats, g2, be2, sc);
    // layer 3
    gemm40_kernel<<<dim3(NN / 32), dim3(8, 32), 0, stream>>>(B, W3, sc, dinv, A);
    agg40_softmax_kernel<<<NN / 4, 256, 0, stream>>>(A, rowptr, srcsorted, dinv, b3, out);
}

// Round 5
// 650.585 us; speedup vs baseline: 1.7868x; 1.1463x over previous
//
#include <hip/hip_runtime.h>
#include <hip/hip_fp16.h>

#define NN   100000
#define NE   1600000
#define FHID 128
#define FO3  40
#define NBUCK 391                 // ceil(NN/256) buckets of 256 nodes
#define NW1   64                  // pass-1 workgroups
#define CH1   (NE / NW1)          // 25000 edges per pass-1 wg
#define GN    (NBUCK * NW1)       // 25024 scan entries
constexpr float EPSV = 1e-5f;

// ---------------- graph prep: 2-level bucket CSR build ----------------

__global__ __launch_bounds__(256) void p1hist_kernel(const int* __restrict__ dst,
                                                     int* __restrict__ G) {
    __shared__ int h[NBUCK];
    int t = threadIdx.x, wg = blockIdx.x;
    for (int i = t; i < NBUCK; i += 256) h[i] = 0;
    __syncthreads();
    int base = wg * CH1;
    for (int e = base + t; e < base + CH1; e += 256)
        atomicAdd(&h[dst[e] >> 8], 1);
    __syncthreads();
    for (int i = t; i < NBUCK; i += 256) G[i * NW1 + wg] = h[i];
}

__global__ __launch_bounds__(1024) void p1scan_kernel(int* __restrict__ G) {
    __shared__ int s[1024];
    const int C = (GN + 1023) / 1024;   // 25
    int t = threadIdx.x;
    int b0 = t * C, b1 = b0 + C; if (b1 > GN) b1 = GN;
    int loc = 0;
    for (int i = b0; i < b1; ++i) loc += G[i];
    s[t] = loc;
    __syncthreads();
    #pragma unroll
    for (int off = 1; off < 1024; off <<= 1) {
        int u = (t >= off) ? s[t - off] : 0;
        __syncthreads();
        s[t] += u;
        __syncthreads();
    }
    int run = (t == 0) ? 0 : s[t - 1];
    for (int i = b0; i < b1; ++i) { int v = G[i]; G[i] = run; run += v; }
}

__global__ __launch_bounds__(256) void p1fill_kernel(const int* __restrict__ src,
                                                     const int* __restrict__ dst,
                                                     const int* __restrict__ G,
                                                     int* __restrict__ ebuf) {
    __shared__ int cur[NBUCK];
    int t = threadIdx.x, wg = blockIdx.x;
    for (int i = t; i < NBUCK; i += 256) cur[i] = G[i * NW1 + wg];
    __syncthreads();
    int base = wg * CH1;
    for (int e = base + t; e < base + CH1; e += 256) {
        int d = dst[e];
        int pos = atomicAdd(&cur[d >> 8], 1);
        ebuf[pos] = src[e] | ((d & 255) << 17);   // src<2^17, pack low dst byte
    }
}

__global__ __launch_bounds__(256) void p2build_kernel(const int* __restrict__ ebuf,
                                                      const int* __restrict__ G,
                                                      int* __restrict__ rowptr,
                                                      int* __restrict__ srcsorted,
                                                      float* __restrict__ dinv) {
    __shared__ int cnt[256];
    __shared__ int s[256];
    __shared__ int cur[256];
    int t = threadIdx.x, b = blockIdx.x;
    int base = G[b * NW1];
    int endp = (b == NBUCK - 1) ? NE : G[(b + 1) * NW1];
    cnt[t] = 0;
    __syncthreads();
    for (int e = base + t; e < endp; e += 256)
        atomicAdd(&cnt[ebuf[e] >> 17], 1);
    __syncthreads();
    int c = cnt[t];
    s[t] = c;
    __syncthreads();
    #pragma unroll
    for (int off = 1; off < 256; off <<= 1) {
        int u = (t >= off) ? s[t - off] : 0;
        __syncthreads();
        s[t] += u;
        __syncthreads();
    }
    int excl = s[t] - c;
    int node = b * 256 + t;
    if (node < NN) {
        rowptr[node] = base + excl;
        dinv[node]   = rsqrtf((float)c + 1.0f);   // +1 self loop
    }
    cur[t] = base + excl;
    __syncthreads();
    for (int e = base + t; e < endp; e += 256) {
        int p = ebuf[e];
        int pos = atomicAdd(&cur[p >> 17], 1);
        srcsorted[pos] = p & 0x1FFFF;
    }
    if (b == NBUCK - 1 && t == 0) rowptr[NN] = NE;
}

// ---------------- batchnorm stats ----------------

__global__ void bnstats_kernel(const float* __restrict__ X, float* __restrict__ stats) {
    int f = threadIdx.x & 127;
    int rg = threadIdx.x >> 7;
    float s = 0.f, s2 = 0.f;
    for (int r = blockIdx.x * 2 + rg; r < NN; r += gridDim.x * 2) {
        float v = X[(size_t)r * 128 + f];
        s += v; s2 += v * v;
    }
    atomicAdd(&stats[f], s);
    atomicAdd(&stats[128 + f], s2);
}

__global__ void bnfinal_kernel(const float* __restrict__ stats, const float* __restrict__ g,
                               const float* __restrict__ be, float* __restrict__ sc) {
    int f = threadIdx.x;
    float mu  = stats[f] * (1.0f / NN);
    float var = stats[128 + f] * (1.0f / NN) - mu * mu;
    float rstd = rsqrtf(var + EPSV);
    float scale = g[f] * rstd;
    sc[f]       = scale;
    sc[128 + f] = be[f] - mu * scale;
}

// ---------------- dense GEMMs (epilogue: *dinv[row], store fp16) ----------------
template<bool BN>
__global__ __launch_bounds__(256) void gemm128_kernel(const float* __restrict__ X,
        const float* __restrict__ W, const float* __restrict__ sc,
        const float* __restrict__ dinv, __half* __restrict__ Y) {
    __shared__ float Ws[128][64];
    __shared__ float Xs[32][132];
    int tx = threadIdx.x, ty = threadIdx.y;
    int tid = ty * 16 + tx;
    int ftile = blockIdx.y * 64;
    int node0 = blockIdx.x * 32;

    for (int idx = tid * 4; idx < 128 * 64; idx += 256 * 4) {
        int k = idx >> 6, c = idx & 63;
        float4 w4 = *(const float4*)(W + (size_t)k * 128 + ftile + c);
        *(float4*)&Ws[k][c] = w4;
    }
    for (int idx = tid * 4; idx < 32 * 128; idx += 256 * 4) {
        int n = idx >> 7, f = idx & 127;
        float4 v = *(const float4*)(X + (size_t)(node0 + n) * 128 + f);
        if constexpr (BN) {
            v.x = fmaxf(fmaf(v.x, sc[f],     sc[128 + f]),     0.f);
            v.y = fmaxf(fmaf(v.y, sc[f + 1], sc[128 + f + 1]), 0.f);
            v.z = fmaxf(fmaf(v.z, sc[f + 2], sc[128 + f + 2]), 0.f);
            v.w = fmaxf(fmaf(v.w, sc[f + 3], sc[128 + f + 3]), 0.f);
        }
        *(float4*)&Xs[n][f] = v;
    }
    __syncthreads();

    float4 a0 = {0,0,0,0}, a1 = {0,0,0,0};
    int n0 = ty, n1 = ty + 16;
    #pragma unroll 4
    for (int k = 0; k < 128; ++k) {
        float4 w = *(float4*)&Ws[k][tx * 4];
        float x0 = Xs[n0][k];
        float x1 = Xs[n1][k];
        a0.x = fmaf(x0, w.x, a0.x); a0.y = fmaf(x0, w.y, a0.y);
        a0.z = fmaf(x0, w.z, a0.z); a0.w = fmaf(x0, w.w, a0.w);
        a1.x = fmaf(x1, w.x, a1.x); a1.y = fmaf(x1, w.y, a1.y);
        a1.z = fmaf(x1, w.z, a1.z); a1.w = fmaf(x1, w.w, a1.w);
    }
    float di0 = dinv[node0 + n0], di1 = dinv[node0 + n1];
    union { __half h[4]; uint2 u; } p0, p1;
    p0.h[0] = __float2half_rn(a0.x * di0); p0.h[1] = __float2half_rn(a0.y * di0);
    p0.h[2] = __float2half_rn(a0.z * di0); p0.h[3] = __float2half_rn(a0.w * di0);
    p1.h[0] = __float2half_rn(a1.x * di1); p1.h[1] = __float2half_rn(a1.y * di1);
    p1.h[2] = __float2half_rn(a1.z * di1); p1.h[3] = __float2half_rn(a1.w * di1);
    *(uint2*)(Y + (size_t)(node0 + n0) * 128 + ftile + tx * 4) = p0.u;
    *(uint2*)(Y + (size_t)(node0 + n1) * 128 + ftile + tx * 4) = p1.u;
}

__global__ __launch_bounds__(256) void gemm40_kernel(const float* __restrict__ X,
        const float* __restrict__ W, const float* __restrict__ sc,
        const float* __restrict__ dinv, __half* __restrict__ Y) {
    __shared__ float Ws[128][40];
    __shared__ float Xs[32][132];
    int tx = threadIdx.x, ty = threadIdx.y;
    int tid = ty * 8 + tx;
    int node0 = blockIdx.x * 32;

    float* wf = &Ws[0][0];
    for (int idx = tid; idx < 128 * 40; idx += 256) wf[idx] = W[idx];
    for (int idx = tid * 4; idx < 32 * 128; idx += 256 * 4) {
        int n = idx >> 7, f = idx & 127;
        float4 v = *(const float4*)(X + (size_t)(node0 + n) * 128 + f);
        v.x = fmaxf(fmaf(v.x, sc[f],     sc[128 + f]),     0.f);
        v.y = fmaxf(fmaf(v.y, sc[f + 1], sc[128 + f + 1]), 0.f);
        v.z = fmaxf(fmaf(v.z, sc[f + 2], sc[128 + f + 2]), 0.f);
        v.w = fmaxf(fmaf(v.w, sc[f + 3], sc[128 + f + 3]), 0.f);
        *(float4*)&Xs[n][f] = v;
    }
    __syncthreads();

    float acc[5] = {0,0,0,0,0};
    int f0 = tx * 5;
    #pragma unroll 4
    for (int k = 0; k < 128; ++k) {
        float xv = Xs[ty][k];
        #pragma unroll
        for (int j = 0; j < 5; ++j) acc[j] = fmaf(xv, Ws[k][f0 + j], acc[j]);
    }
    float di = dinv[node0 + ty];
    __half* yp = Y + (size_t)(node0 + ty) * 40 + f0;
    #pragma unroll
    for (int j = 0; j < 5; ++j) yp[j] = __float2half_rn(acc[j] * di);
}

// ---------------- aggregation (H fp16, rows pre-scaled by dinv[src]) ----------------
__global__ __launch_bounds__(256) void agg128_kernel(const __half* __restrict__ H,
        const int* __restrict__ rowptr, const int* __restrict__ srcs,
        const float* __restrict__ dinv, const float* __restrict__ bias,
        float* __restrict__ out) {
    int wave = threadIdx.x >> 6;
    int lane = threadIdx.x & 63;
    int node = blockIdx.x * 4 + wave;
    int beg = rowptr[node], end = rowptr[node + 1];
    int c = lane * 2;
    float a0 = 0.f, a1 = 0.f, b0 = 0.f, b1 = 0.f;
    int e = beg;
    for (; e + 3 < end; e += 4) {
        int s0 = srcs[e], s1 = srcs[e + 1], s2 = srcs[e + 2], s3 = srcs[e + 3];
        float2 f0 = __half22float2(*(const __half2*)(H + (size_t)s0 * 128 + c));
        float2 f1 = __half22float2(*(const __half2*)(H + (size_t)s1 * 128 + c));
        float2 f2 = __half22float2(*(const __half2*)(H + (size_t)s2 * 128 + c));
        float2 f3 = __half22float2(*(const __half2*)(H + (size_t)s3 * 128 + c));
        a0 += f0.x + f1.x; a1 += f0.y + f1.y;
        b0 += f2.x + f3.x; b1 += f2.y + f3.y;
    }
    for (; e < end; ++e) {
        int s = srcs[e];
        float2 f = __half22float2(*(const __half2*)(H + (size_t)s * 128 + c));
        a0 += f.x; a1 += f.y;
    }
    float di = dinv[node];
    float2 hs = __half22float2(*(const __half2*)(H + (size_t)node * 128 + c));
    a0 = di * (a0 + b0 + hs.x) + bias[c];
    a1 = di * (a1 + b1 + hs.y) + bias[c + 1];
    *(float2*)(out + (size_t)node * 128 + c) = make_float2(a0, a1);
}

__global__ __launch_bounds__(256) void agg40_softmax_kernel(const __half* __restrict__ H,
        const int* __restrict__ rowptr, const int* __restrict__ srcs,
        const float* __restrict__ dinv, const float* __restrict__ bias,
        float* __restrict__ out) {
    int wave = threadIdx.x >> 6;
    int lane = threadIdx.x & 63;
    int node = blockIdx.x * 4 + wave;
    int beg = rowptr[node], end = rowptr[node + 1];
    bool act = lane < 40;
    int ln = act ? lane : 0;
    float a0 = 0.f, a1 = 0.f, a2 = 0.f, a3 = 0.f;
    int e = beg;
    for (; e + 3 < end; e += 4) {
        int s0 = srcs[e], s1 = srcs[e + 1], s2 = srcs[e + 2], s3 = srcs[e + 3];
        a0 += __half2float(H[(size_t)s0 * 40 + ln]);
        a1 += __half2float(H[(size_t)s1 * 40 + ln]);
        a2 += __half2float(H[(size_t)s2 * 40 + ln]);
        a3 += __half2float(H[(size_t)s3 * 40 + ln]);
    }
    for (; e < end; ++e) a0 += __half2float(H[(size_t)srcs[e] * 40 + ln]);
    float di = dinv[node];
    float hs = __half2float(H[(size_t)node * 40 + ln]);
    float v = act ? (di * (a0 + a1 + a2 + a3 + hs) + bias[ln]) : -3.0e38f;
    float m = v;
    #pragma unroll
    for (int off = 32; off > 0; off >>= 1) m = fmaxf(m, __shfl_xor(m, off));
    float ev = act ? expf(v - m) : 0.f;
    float ssum = ev;
    #pragma unroll
    for (int off = 32; off > 0; off >>= 1) ssum += __shfl_xor(ssum, off);
    if (act) out[(size_t)node * 40 + lane] = ev / ssum;
}

// ---------------- launch ----------------

extern "C" void kernel_launch(void* const* d_in, const int* in_sizes, int n_in,
                              void* d_out, int out_size, void* d_ws, size_t ws_size,
                              hipStream_t stream) {
    const float* x   = (const float*)d_in[0];
    const int*   ei  = (const int*)d_in[1];
    const float* W1  = (const float*)d_in[2];
    const float* b1  = (const float*)d_in[3];
    const float* g1  = (const float*)d_in[4];
    const float* be1 = (const float*)d_in[5];
    const float* W2  = (const float*)d_in[6];
    const float* b2  = (const float*)d_in[7];
    const float* g2  = (const float*)d_in[8];
    const float* be2 = (const float*)d_in[9];
    const float* W3  = (const float*)d_in[10];
    const float* b3  = (const float*)d_in[11];
    float* out = (float*)d_out;
    const int* src = ei;
    const int* dst = ei + NE;

    char* p = (char*)d_ws;
    auto alloc = [&](size_t bytes) { char* r = p; p += (bytes + 255) & ~255ull; return r; };
    int*    rowptr    = (int*)   alloc((size_t)(NN + 1) * 4);
    int*    srcsorted = (int*)   alloc((size_t)NE * 4);
    float*  dinv      = (float*) alloc((size_t)NN * 4);
    float*  stats     = (float*) alloc(256 * 4);
    float*  sc        = (float*) alloc(256 * 4);
    int*    G         = (int*)   alloc((size_t)GN * 4);
    __half* A         = (__half*)alloc((size_t)NN * 128 * 2);   // fp16 gather buffer
    float*  B         = (float*) alloc((size_t)NN * 128 * 4);
    int*    ebuf      = (int*)A;   // A unused until layer-1 GEMM (NE*4 <= NN*128*2)

    // graph prep
    p1hist_kernel<<<NW1, 256, 0, stream>>>(dst, G);
    p1scan_kernel<<<1, 1024, 0, stream>>>(G);
    p1fill_kernel<<<NW1, 256, 0, stream>>>(src, dst, G, ebuf);
    p2build_kernel<<<NBUCK, 256, 0, stream>>>(ebuf, G, rowptr, srcsorted, dinv);

    dim3 gb(16, 16);
    // layer 1
    gemm128_kernel<false><<<dim3(NN / 32, 2), gb, 0, stream>>>(x, W1, nullptr, dinv, A);
    agg128_kernel<<<NN / 4, 256, 0, stream>>>(A, rowptr, srcsorted, dinv, b1, B);
    hipMemsetAsync(stats, 0, 256 * 4, stream);
    bnstats_kernel<<<1024, 256, 0, stream>>>(B, stats);
    bnfinal_kernel<<<1, 128, 0, stream>>>(stats, g1, be1, sc);
    // layer 2
    gemm128_kernel<true><<<dim3(NN / 32, 2), gb, 0, stream>>>(B, W2, sc, dinv, A);
    agg128_kernel<<<NN / 4, 256, 0, stream>>>(A, rowptr, srcsorted, dinv, b2, B);
    hipMemsetAsync(stats, 0, 256 * 4, stream);
    bnstats_kernel<<<1024, 256, 0, stream>>>(B, stats);
    bnfinal_kernel<<<1, 128, 0, stream>>>(stats, g2, be2, sc);
    // layer 3
    gemm40_kernel<<<dim3(NN / 32), dim3(8, 32), 0, stream>>>(B, W3, sc, dinv, A);
    agg40_softmax_kernel<<<NN / 4, 256, 0, stream>>>(A, rowptr, srcsorted, dinv, b3, out);
}

// Round 6
// 567.278 us; speedup vs baseline: 2.0492x; 1.1469x over previous
//
#include <hip/hip_runtime.h>
#include <hip/hip_fp16.h>

#define NN   100000
#define NE   1600000
#define FHID 128
#define FO3  40
#define NBUCK 391                 // ceil(NN/256) buckets of 256 nodes
#define NW1   512                 // pass-1 workgroups (widened from 64)
#define CH1   (NE / NW1)          // 3125 edges per pass-1 wg
#define GN    (NBUCK * NW1)       // 200192 scan entries
#define SC    512
#define SNB   (GN / SC)           // 391 scan blocks (GN divisible by 512)
constexpr float EPSV = 1e-5f;

// ---------------- graph prep: 2-level bucket CSR build ----------------

__global__ __launch_bounds__(256) void p1hist_kernel(const int* __restrict__ dst,
                                                     int* __restrict__ G) {
    __shared__ int h[NBUCK];
    int t = threadIdx.x, wg = blockIdx.x;
    for (int i = t; i < NBUCK; i += 256) h[i] = 0;
    __syncthreads();
    int base = wg * CH1;
    for (int e = base + t; e < base + CH1; e += 256)
        atomicAdd(&h[dst[e] >> 8], 1);
    __syncthreads();
    for (int i = t; i < NBUCK; i += 256) G[i * NW1 + wg] = h[i];
}

// ---- 3-phase hierarchical exclusive scan of G[GN] (in place) ----

__global__ __launch_bounds__(256) void gscan1_kernel(const int* __restrict__ G,
                                                     int* __restrict__ bsum) {
    __shared__ int red[256];
    int t = threadIdx.x;
    int base = blockIdx.x * SC + t * 2;
    red[t] = G[base] + G[base + 1];
    __syncthreads();
    #pragma unroll
    for (int off = 128; off > 0; off >>= 1) {
        if (t < off) red[t] += red[t + off];
        __syncthreads();
    }
    if (t == 0) bsum[blockIdx.x] = red[0];
}

__global__ __launch_bounds__(512) void gscan2_kernel(const int* __restrict__ bsum,
                                                     int* __restrict__ boff) {
    __shared__ int s[512];
    int t = threadIdx.x;
    int v = (t < SNB) ? bsum[t] : 0;
    s[t] = v;
    __syncthreads();
    #pragma unroll
    for (int off = 1; off < 512; off <<= 1) {
        int u = (t >= off) ? s[t - off] : 0;
        __syncthreads();
        s[t] += u;
        __syncthreads();
    }
    if (t < SNB) boff[t] = s[t] - v;   // exclusive
}

__global__ __launch_bounds__(256) void gscan3_kernel(int* __restrict__ G,
                                                     const int* __restrict__ boff) {
    __shared__ int s[256];
    int t = threadIdx.x;
    int base = blockIdx.x * SC + t * 2;
    int c0 = G[base], c1 = G[base + 1];
    int pair = c0 + c1;
    s[t] = pair;
    __syncthreads();
    #pragma unroll
    for (int off = 1; off < 256; off <<= 1) {
        int u = (t >= off) ? s[t - off] : 0;
        __syncthreads();
        s[t] += u;
        __syncthreads();
    }
    int excl = boff[blockIdx.x] + s[t] - pair;
    G[base]     = excl;
    G[base + 1] = excl + c0;
}

__global__ __launch_bounds__(256) void p1fill_kernel(const int* __restrict__ src,
                                                     const int* __restrict__ dst,
                                                     const int* __restrict__ G,
                                                     int* __restrict__ ebuf) {
    __shared__ int cur[NBUCK];
    int t = threadIdx.x, wg = blockIdx.x;
    for (int i = t; i < NBUCK; i += 256) cur[i] = G[i * NW1 + wg];
    __syncthreads();
    int base = wg * CH1;
    for (int e = base + t; e < base + CH1; e += 256) {
        int d = dst[e];
        int pos = atomicAdd(&cur[d >> 8], 1);
        ebuf[pos] = src[e] | ((d & 255) << 17);   // src<2^17, pack low dst byte
    }
}

__global__ __launch_bounds__(256) void p2build_kernel(const int* __restrict__ ebuf,
                                                      const int* __restrict__ G,
                                                      int* __restrict__ rowptr,
                                                      int* __restrict__ srcsorted,
                                                      float* __restrict__ dinv) {
    __shared__ int cnt[256];
    __shared__ int s[256];
    __shared__ int cur[256];
    int t = threadIdx.x, b = blockIdx.x;
    int base = G[b * NW1];
    int endp = (b == NBUCK - 1) ? NE : G[(b + 1) * NW1];
    cnt[t] = 0;
    __syncthreads();
    for (int e = base + t; e < endp; e += 256)
        atomicAdd(&cnt[ebuf[e] >> 17], 1);
    __syncthreads();
    int c = cnt[t];
    s[t] = c;
    __syncthreads();
    #pragma unroll
    for (int off = 1; off < 256; off <<= 1) {
        int u = (t >= off) ? s[t - off] : 0;
        __syncthreads();
        s[t] += u;
        __syncthreads();
    }
    int excl = s[t] - c;
    int node = b * 256 + t;
    if (node < NN) {
        rowptr[node] = base + excl;
        dinv[node]   = rsqrtf((float)c + 1.0f);   // +1 self loop
    }
    cur[t] = base + excl;
    __syncthreads();
    for (int e = base + t; e < endp; e += 256) {
        int p = ebuf[e];
        int pos = atomicAdd(&cur[p >> 17], 1);
        srcsorted[pos] = p & 0x1FFFF;
    }
    if (b == NBUCK - 1 && t == 0) rowptr[NN] = NE;
}

// ---------------- batchnorm stats ----------------

__global__ void bnstats_kernel(const float* __restrict__ X, float* __restrict__ stats) {
    int f = threadIdx.x & 127;
    int rg = threadIdx.x >> 7;
    float s = 0.f, s2 = 0.f;
    for (int r = blockIdx.x * 2 + rg; r < NN; r += gridDim.x * 2) {
        float v = X[(size_t)r * 128 + f];
        s += v; s2 += v * v;
    }
    atomicAdd(&stats[f], s);
    atomicAdd(&stats[128 + f], s2);
}

__global__ void bnfinal_kernel(const float* __restrict__ stats, const float* __restrict__ g,
                               const float* __restrict__ be, float* __restrict__ sc) {
    int f = threadIdx.x;
    float mu  = stats[f] * (1.0f / NN);
    float var = stats[128 + f] * (1.0f / NN) - mu * mu;
    float rstd = rsqrtf(var + EPSV);
    float scale = g[f] * rstd;
    sc[f]       = scale;
    sc[128 + f] = be[f] - mu * scale;
}

// ---------------- dense GEMMs (epilogue: *dinv[row], store fp16) ----------------
template<bool BN>
__global__ __launch_bounds__(256) void gemm128_kernel(const float* __restrict__ X,
        const float* __restrict__ W, const float* __restrict__ sc,
        const float* __restrict__ dinv, __half* __restrict__ Y) {
    __shared__ float Ws[128][64];
    __shared__ float Xs[32][132];
    int tx = threadIdx.x, ty = threadIdx.y;
    int tid = ty * 16 + tx;
    int ftile = blockIdx.y * 64;
    int node0 = blockIdx.x * 32;

    for (int idx = tid * 4; idx < 128 * 64; idx += 256 * 4) {
        int k = idx >> 6, c = idx & 63;
        float4 w4 = *(const float4*)(W + (size_t)k * 128 + ftile + c);
        *(float4*)&Ws[k][c] = w4;
    }
    for (int idx = tid * 4; idx < 32 * 128; idx += 256 * 4) {
        int n = idx >> 7, f = idx & 127;
        float4 v = *(const float4*)(X + (size_t)(node0 + n) * 128 + f);
        if constexpr (BN) {
            v.x = fmaxf(fmaf(v.x, sc[f],     sc[128 + f]),     0.f);
            v.y = fmaxf(fmaf(v.y, sc[f + 1], sc[128 + f + 1]), 0.f);
            v.z = fmaxf(fmaf(v.z, sc[f + 2], sc[128 + f + 2]), 0.f);
            v.w = fmaxf(fmaf(v.w, sc[f + 3], sc[128 + f + 3]), 0.f);
        }
        *(float4*)&Xs[n][f] = v;
    }
    __syncthreads();

    float4 a0 = {0,0,0,0}, a1 = {0,0,0,0};
    int n0 = ty, n1 = ty + 16;
    #pragma unroll 4
    for (int k = 0; k < 128; ++k) {
        float4 w = *(float4*)&Ws[k][tx * 4];
        float x0 = Xs[n0][k];
        float x1 = Xs[n1][k];
        a0.x = fmaf(x0, w.x, a0.x); a0.y = fmaf(x0, w.y, a0.y);
        a0.z = fmaf(x0, w.z, a0.z); a0.w = fmaf(x0, w.w, a0.w);
        a1.x = fmaf(x1, w.x, a1.x); a1.y = fmaf(x1, w.y, a1.y);
        a1.z = fmaf(x1, w.z, a1.z); a1.w = fmaf(x1, w.w, a1.w);
    }
    float di0 = dinv[node0 + n0], di1 = dinv[node0 + n1];
    union { __half h[4]; uint2 u; } p0, p1;
    p0.h[0] = __float2half_rn(a0.x * di0); p0.h[1] = __float2half_rn(a0.y * di0);
    p0.h[2] = __float2half_rn(a0.z * di0); p0.h[3] = __float2half_rn(a0.w * di0);
    p1.h[0] = __float2half_rn(a1.x * di1); p1.h[1] = __float2half_rn(a1.y * di1);
    p1.h[2] = __float2half_rn(a1.z * di1); p1.h[3] = __float2half_rn(a1.w * di1);
    *(uint2*)(Y + (size_t)(node0 + n0) * 128 + ftile + tx * 4) = p0.u;
    *(uint2*)(Y + (size_t)(node0 + n1) * 128 + ftile + tx * 4) = p1.u;
}

__global__ __launch_bounds__(256) void gemm40_kernel(const float* __restrict__ X,
        const float* __restrict__ W, const float* __restrict__ sc,
        const float* __restrict__ dinv, __half* __restrict__ Y) {
    __shared__ float Ws[128][40];
    __shared__ float Xs[32][132];
    int tx = threadIdx.x, ty = threadIdx.y;
    int tid = ty * 8 + tx;
    int node0 = blockIdx.x * 32;

    float* wf = &Ws[0][0];
    for (int idx = tid; idx < 128 * 40; idx += 256) wf[idx] = W[idx];
    for (int idx = tid * 4; idx < 32 * 128; idx += 256 * 4) {
        int n = idx >> 7, f = idx & 127;
        float4 v = *(const float4*)(X + (size_t)(node0 + n) * 128 + f);
        v.x = fmaxf(fmaf(v.x, sc[f],     sc[128 + f]),     0.f);
        v.y = fmaxf(fmaf(v.y, sc[f + 1], sc[128 + f + 1]), 0.f);
        v.z = fmaxf(fmaf(v.z, sc[f + 2], sc[128 + f + 2]), 0.f);
        v.w = fmaxf(fmaf(v.w, sc[f + 3], sc[128 + f + 3]), 0.f);
        *(float4*)&Xs[n][f] = v;
    }
    __syncthreads();

    float acc[5] = {0,0,0,0,0};
    int f0 = tx * 5;
    #pragma unroll 4
    for (int k = 0; k < 128; ++k) {
        float xv = Xs[ty][k];
        #pragma unroll
        for (int j = 0; j < 5; ++j) acc[j] = fmaf(xv, Ws[k][f0 + j], acc[j]);
    }
    float di = dinv[node0 + ty];
    __half* yp = Y + (size_t)(node0 + ty) * 40 + f0;
    #pragma unroll
    for (int j = 0; j < 5; ++j) yp[j] = __float2half_rn(acc[j] * di);
}

// ---------------- aggregation (H fp16, rows pre-scaled by dinv[src]) ----------------
__global__ __launch_bounds__(256) void agg128_kernel(const __half* __restrict__ H,
        const int* __restrict__ rowptr, const int* __restrict__ srcs,
        const float* __restrict__ dinv, const float* __restrict__ bias,
        float* __restrict__ out) {
    int wave = threadIdx.x >> 6;
    int lane = threadIdx.x & 63;
    int node = blockIdx.x * 4 + wave;
    int beg = rowptr[node], end = rowptr[node + 1];
    int c = lane * 2;
    float a0 = 0.f, a1 = 0.f, b0 = 0.f, b1 = 0.f;
    int e = beg;
    for (; e + 3 < end; e += 4) {
        int s0 = srcs[e], s1 = srcs[e + 1], s2 = srcs[e + 2], s3 = srcs[e + 3];
        float2 f0 = __half22float2(*(const __half2*)(H + (size_t)s0 * 128 + c));
        float2 f1 = __half22float2(*(const __half2*)(H + (size_t)s1 * 128 + c));
        float2 f2 = __half22float2(*(const __half2*)(H + (size_t)s2 * 128 + c));
        float2 f3 = __half22float2(*(const __half2*)(H + (size_t)s3 * 128 + c));
        a0 += f0.x + f1.x; a1 += f0.y + f1.y;
        b0 += f2.x + f3.x; b1 += f2.y + f3.y;
    }
    for (; e < end; ++e) {
        int s = srcs[e];
        float2 f = __half22float2(*(const __half2*)(H + (size_t)s * 128 + c));
        a0 += f.x; a1 += f.y;
    }
    float di = dinv[node];
    float2 hs = __half22float2(*(const __half2*)(H + (size_t)node * 128 + c));
    a0 = di * (a0 + b0 + hs.x) + bias[c];
    a1 = di * (a1 + b1 + hs.y) + bias[c + 1];
    *(float2*)(out + (size_t)node * 128 + c) = make_float2(a0, a1);
}

__global__ __launch_bounds__(256) void agg40_softmax_kernel(const __half* __restrict__ H,
        const int* __restrict__ rowptr, const int* __restrict__ srcs,
        const float* __restrict__ dinv, const float* __restrict__ bias,
        float* __restrict__ out) {
    int wave = threadIdx.x >> 6;
    int lane = threadIdx.x & 63;
    int node = blockIdx.x * 4 + wave;
    int beg = rowptr[node], end = rowptr[node + 1];
    bool act = lane < 40;
    int ln = act ? lane : 0;
    float a0 = 0.f, a1 = 0.f, a2 = 0.f, a3 = 0.f;
    int e = beg;
    for (; e + 3 < end; e += 4) {
        int s0 = srcs[e], s1 = srcs[e + 1], s2 = srcs[e + 2], s3 = srcs[e + 3];
        a0 += __half2float(H[(size_t)s0 * 40 + ln]);
        a1 += __half2float(H[(size_t)s1 * 40 + ln]);
        a2 += __half2float(H[(size_t)s2 * 40 + ln]);
        a3 += __half2float(H[(size_t)s3 * 40 + ln]);
    }
    for (; e < end; ++e) a0 += __half2float(H[(size_t)srcs[e] * 40 + ln]);
    float di = dinv[node];
    float hs = __half2float(H[(size_t)node * 40 + ln]);
    float v = act ? (di * (a0 + a1 + a2 + a3 + hs) + bias[ln]) : -3.0e38f;
    float m = v;
    #pragma unroll
    for (int off = 32; off > 0; off >>= 1) m = fmaxf(m, __shfl_xor(m, off));
    float ev = act ? expf(v - m) : 0.f;
    float ssum = ev;
    #pragma unroll
    for (int off = 32; off > 0; off >>= 1) ssum += __shfl_xor(ssum, off);
    if (act) out[(size_t)node * 40 + lane] = ev / ssum;
}

// ---------------- launch ----------------

extern "C" void kernel_launch(void* const* d_in, const int* in_sizes, int n_in,
                              void* d_out, int out_size, void* d_ws, size_t ws_size,
                              hipStream_t stream) {
    const float* x   = (const float*)d_in[0];
    const int*   ei  = (const int*)d_in[1];
    const float* W1  = (const float*)d_in[2];
    const float* b1  = (const float*)d_in[3];
    const float* g1  = (const float*)d_in[4];
    const float* be1 = (const float*)d_in[5];
    const float* W2  = (const float*)d_in[6];
    const float* b2  = (const float*)d_in[7];
    const float* g2  = (const float*)d_in[8];
    const float* be2 = (const float*)d_in[9];
    const float* W3  = (const float*)d_in[10];
    const float* b3  = (const float*)d_in[11];
    float* out = (float*)d_out;
    const int* src = ei;
    const int* dst = ei + NE;

    char* p = (char*)d_ws;
    auto alloc = [&](size_t bytes) { char* r = p; p += (bytes + 255) & ~255ull; return r; };
    int*    rowptr    = (int*)   alloc((size_t)(NN + 1) * 4);
    int*    srcsorted = (int*)   alloc((size_t)NE * 4);
    float*  dinv      = (float*) alloc((size_t)NN * 4);
    float*  stats     = (float*) alloc(256 * 4);
    float*  sc        = (float*) alloc(256 * 4);
    int*    G         = (int*)   alloc((size_t)GN * 4);
    int*    bsum      = (int*)   alloc((size_t)SNB * 4);
    int*    boff      = (int*)   alloc((size_t)SNB * 4);
    __half* A         = (__half*)alloc((size_t)NN * 128 * 2);   // fp16 gather buffer
    float*  B         = (float*) alloc((size_t)NN * 128 * 4);
    int*    ebuf      = (int*)A;   // A unused until layer-1 GEMM (NE*4 <= NN*128*2)

    // graph prep
    p1hist_kernel<<<NW1, 256, 0, stream>>>(dst, G);
    gscan1_kernel<<<SNB, 256, 0, stream>>>(G, bsum);
    gscan2_kernel<<<1, 512, 0, stream>>>(bsum, boff);
    gscan3_kernel<<<SNB, 256, 0, stream>>>(G, boff);
    p1fill_kernel<<<NW1, 256, 0, stream>>>(src, dst, G, ebuf);
    p2build_kernel<<<NBUCK, 256, 0, stream>>>(ebuf, G, rowptr, srcsorted, dinv);

    dim3 gb(16, 16);
    // layer 1
    gemm128_kernel<false><<<dim3(NN / 32, 2), gb, 0, stream>>>(x, W1, nullptr, dinv, A);
    agg128_kernel<<<NN / 4, 256, 0, stream>>>(A, rowptr, srcsorted, dinv, b1, B);
    hipMemsetAsync(stats, 0, 256 * 4, stream);
    bnstats_kernel<<<1024, 256, 0, stream>>>(B, stats);
    bnfinal_kernel<<<1, 128, 0, stream>>>(stats, g1, be1, sc);
    // layer 2
    gemm128_kernel<true><<<dim3(NN / 32, 2), gb, 0, stream>>>(B, W2, sc, dinv, A);
    agg128_kernel<<<NN / 4, 256, 0, stream>>>(A, rowptr, srcsorted, dinv, b2, B);
    hipMemsetAsync(stats, 0, 256 * 4, stream);
    bnstats_kernel<<<1024, 256, 0, stream>>>(B, stats);
    bnfinal_kernel<<<1, 128, 0, stream>>>(stats, g2, be2, sc);
    // layer 3
    gemm40_kernel<<<dim3(NN / 32), dim3(8, 32), 0, stream>>>(B, W3, sc, dinv, A);
    agg40_softmax_kernel<<<NN / 4, 256, 0, stream>>>(A, rowptr, srcsorted, dinv, b3, out);
}